// Round 1
// baseline (1607.526 us; speedup 1.0000x reference)
//
#include <hip/hip_runtime.h>
#include <hip/hip_bf16.h>

// GraphSAGE 2-layer + BN + ReLU + MLP classifier, fp32.
// Pipeline: CSR build (hist -> scan -> fill), then per layer:
//   aggregate(mean over in-neighbors) -> dual GEMM (+bias, +stats) -> BN params -> norm+relu
// then classifier (128->64 relu ->1).

#define HID 128
#define TILE_ROWS 16

__global__ void hist_kernel(const int* __restrict__ tgt, int* __restrict__ deg, int e) {
    int i = blockIdx.x * blockDim.x + threadIdx.x;
    if (i < e) atomicAdd(&deg[tgt[i]], 1);
}

// single-block exclusive scan of deg[0..n) -> off[0..n], off[n]=total
__global__ void scan_kernel(const int* __restrict__ deg, int* __restrict__ off, int n) {
    __shared__ int wsum[16];
    __shared__ int wpre[16];
    __shared__ int carry;
    int tid = threadIdx.x;
    int lane = tid & 63;
    int wid = tid >> 6;
    if (tid == 0) carry = 0;
    __syncthreads();
    for (int base = 0; base < n; base += 1024) {
        int i = base + tid;
        int v = (i < n) ? deg[i] : 0;
        int s = v;
        #pragma unroll
        for (int o = 1; o < 64; o <<= 1) {
            int t = __shfl_up(s, o, 64);
            if (lane >= o) s += t;
        }
        if (lane == 63) wsum[wid] = s;
        __syncthreads();
        if (wid == 0 && lane < 16) {
            int ws = wsum[lane];
            int ss = ws;
            #pragma unroll
            for (int o = 1; o < 16; o <<= 1) {
                int t = __shfl_up(ss, o, 64);
                if (lane >= o) ss += t;
            }
            wpre[lane] = ss - ws;  // exclusive prefix of wave sums
        }
        __syncthreads();
        int excl = carry + wpre[wid] + s - v;
        if (i < n) off[i] = excl;
        __syncthreads();
        if (tid == 1023) carry = carry + wpre[15] + wsum[15];
        __syncthreads();
    }
    if (tid == 0) off[n] = carry;
}

__global__ void fill_kernel(const int* __restrict__ src, const int* __restrict__ tgt,
                            const int* __restrict__ off, int* __restrict__ cnt,
                            int* __restrict__ csr, int e) {
    int i = blockIdx.x * blockDim.x + threadIdx.x;
    if (i < e) {
        int t = tgt[i];
        int slot = off[t] + atomicAdd(&cnt[t], 1);
        csr[slot] = src[i];
    }
}

// one wave per node: mean of neighbor rows (float2 per lane = 512B coalesced per row)
__global__ void aggregate_kernel(const float* __restrict__ feat, const int* __restrict__ off,
                                 const int* __restrict__ csr, float* __restrict__ outmean, int n) {
    int wv = (blockIdx.x * blockDim.x + threadIdx.x) >> 6;
    int lane = threadIdx.x & 63;
    if (wv >= n) return;
    int beg = off[wv], end = off[wv + 1];
    const float2* base = (const float2*)feat;
    float2 acc = {0.f, 0.f};
    for (int j = beg; j < end; ++j) {
        int s = csr[j];
        float2 v = base[(size_t)s * 64 + lane];
        acc.x += v.x;
        acc.y += v.y;
    }
    float inv = 1.0f / fmaxf((float)(end - beg), 1.0f);
    float2 m = {acc.x * inv, acc.y * inv};
    ((float2*)outmean)[(size_t)wv * 64 + lane] = m;
}

// h = mean @ Wn + b + x @ Wr ; also accumulate per-column sum/sumsq into stats.
// Weights staged in LDS (128KB), 16-row input tiles in LDS (16KB). 4 rows/wave.
// Safe for hout == meanbuf (rows staged to LDS before overwrite, tiles disjoint).
__global__ __launch_bounds__(256, 1) void sage_linear_kernel(
    const float* __restrict__ meanbuf, const float* __restrict__ xbuf,
    const float* __restrict__ Wn, const float* __restrict__ bias,
    const float* __restrict__ Wr, float* __restrict__ hout,
    float* __restrict__ stats, int n) {
    __shared__ float sWn[HID * HID];
    __shared__ float sWr[HID * HID];
    __shared__ float sRow[2 * TILE_ROWS * HID];
    for (int i = threadIdx.x; i < HID * HID / 4; i += 256) {
        ((float4*)sWn)[i] = ((const float4*)Wn)[i];
        ((float4*)sWr)[i] = ((const float4*)Wr)[i];
    }
    int lane = threadIdx.x & 63;
    int wid = threadIdx.x >> 6;
    float2 bb = ((const float2*)bias)[lane];
    float2 ssum = {0.f, 0.f}, ssq = {0.f, 0.f};
    int ntiles = (n + TILE_ROWS - 1) / TILE_ROWS;
    for (int tile = blockIdx.x; tile < ntiles; tile += gridDim.x) {
        int row0 = tile * TILE_ROWS;
        int valid = min(TILE_ROWS, n - row0);
        int nvalid4 = valid * (HID / 4);
        __syncthreads();
        {
            const float4* msrc = (const float4*)(meanbuf + (size_t)row0 * HID);
            const float4* xsrc = (const float4*)(xbuf + (size_t)row0 * HID);
            float4* mdst = (float4*)sRow;
            float4* xdst = (float4*)(sRow + TILE_ROWS * HID);
            float4 z = {0.f, 0.f, 0.f, 0.f};
            for (int i = threadIdx.x; i < TILE_ROWS * HID / 4; i += 256) {
                mdst[i] = (i < nvalid4) ? msrc[i] : z;
                xdst[i] = (i < nvalid4) ? xsrc[i] : z;
            }
        }
        __syncthreads();
        float2 acc[4];
        #pragma unroll
        for (int r = 0; r < 4; ++r) acc[r] = bb;
        const float* mrow = sRow + (wid * 4) * HID;
        const float* xrow = sRow + TILE_ROWS * HID + (wid * 4) * HID;
        #pragma unroll 2
        for (int k = 0; k < HID; k += 4) {
            float4 m4[4], x4[4];
            #pragma unroll
            for (int r = 0; r < 4; ++r) {
                m4[r] = *(const float4*)(mrow + r * HID + k);
                x4[r] = *(const float4*)(xrow + r * HID + k);
            }
            #pragma unroll
            for (int kk = 0; kk < 4; ++kk) {
                float2 wn = *(const float2*)(sWn + (k + kk) * HID + 2 * lane);
                float2 wr = *(const float2*)(sWr + (k + kk) * HID + 2 * lane);
                #pragma unroll
                for (int r = 0; r < 4; ++r) {
                    float mv = ((const float*)&m4[r])[kk];
                    float xv = ((const float*)&x4[r])[kk];
                    acc[r].x = fmaf(mv, wn.x, acc[r].x);
                    acc[r].x = fmaf(xv, wr.x, acc[r].x);
                    acc[r].y = fmaf(mv, wn.y, acc[r].y);
                    acc[r].y = fmaf(xv, wr.y, acc[r].y);
                }
            }
        }
        #pragma unroll
        for (int r = 0; r < 4; ++r) {
            int lr = wid * 4 + r;
            if (lr < valid) {
                ((float2*)hout)[(size_t)(row0 + lr) * 64 + lane] = acc[r];
                ssum.x += acc[r].x; ssum.y += acc[r].y;
                ssq.x += acc[r].x * acc[r].x; ssq.y += acc[r].y * acc[r].y;
            }
        }
    }
    // reduce stats across the 4 waves (reuse sRow) then atomics
    __syncthreads();
    float2* redS = (float2*)sRow;
    float2* redQ = ((float2*)sRow) + 256;
    redS[wid * 64 + lane] = ssum;
    redQ[wid * 64 + lane] = ssq;
    __syncthreads();
    if (wid == 0) {
        float2 ts = redS[lane], tq = redQ[lane];
        #pragma unroll
        for (int w = 1; w < 4; ++w) {
            ts.x += redS[w * 64 + lane].x; ts.y += redS[w * 64 + lane].y;
            tq.x += redQ[w * 64 + lane].x; tq.y += redQ[w * 64 + lane].y;
        }
        atomicAdd(&stats[2 * lane], ts.x);
        atomicAdd(&stats[2 * lane + 1], ts.y);
        atomicAdd(&stats[HID + 2 * lane], tq.x);
        atomicAdd(&stats[HID + 2 * lane + 1], tq.y);
    }
}

__global__ void bnparam_kernel(const float* __restrict__ stats, const float* __restrict__ g,
                               const float* __restrict__ be, float* __restrict__ params, float invn) {
    int j = threadIdx.x;  // 128
    float mu = stats[j] * invn;
    float var = stats[HID + j] * invn - mu * mu;
    float a = g[j] * rsqrtf(var + 1e-5f);
    params[j] = a;
    params[HID + j] = be[j] - mu * a;
}

__global__ void norm_relu_kernel(float* __restrict__ h, const float* __restrict__ params, int total) {
    int i = blockIdx.x * blockDim.x + threadIdx.x;
    if (i >= total) return;
    int cp = i & 63;
    float a0 = params[2 * cp], a1 = params[2 * cp + 1];
    float b0 = params[HID + 2 * cp], b1 = params[HID + 2 * cp + 1];
    float2 v = ((float2*)h)[i];
    v.x = fmaxf(fmaf(v.x, a0, b0), 0.f);
    v.y = fmaxf(fmaf(v.y, a1, b1), 0.f);
    ((float2*)h)[i] = v;
}

// per-row: out = relu(hn @ Wc1 + bc1) @ Wc2 + bc2 ; one wave per row, Wc1 in LDS
__global__ __launch_bounds__(256) void classifier_kernel(
    const float* __restrict__ hn, const float* __restrict__ Wc1, const float* __restrict__ bc1,
    const float* __restrict__ Wc2, const float* __restrict__ bc2, float* __restrict__ out, int n) {
    __shared__ float sW[HID * 64];
    __shared__ float sW2[64];
    for (int i = threadIdx.x; i < HID * 64 / 4; i += 256) ((float4*)sW)[i] = ((const float4*)Wc1)[i];
    if (threadIdx.x < 64) sW2[threadIdx.x] = Wc2[threadIdx.x];
    __syncthreads();
    int lane = threadIdx.x & 63;
    float b1v = bc1[lane];
    float b2v = bc2[0];
    int nwaves = (gridDim.x * blockDim.x) >> 6;
    int gw = (blockIdx.x * blockDim.x + threadIdx.x) >> 6;
    for (int row = gw; row < n; row += nwaves) {
        float2 hv = ((const float2*)hn)[(size_t)row * 64 + lane];
        float acc = b1v;
        #pragma unroll
        for (int k2 = 0; k2 < 64; ++k2) {
            float hx = __shfl(hv.x, k2, 64);
            float hy = __shfl(hv.y, k2, 64);
            acc = fmaf(hx, sW[(2 * k2) * 64 + lane], acc);
            acc = fmaf(hy, sW[(2 * k2 + 1) * 64 + lane], acc);
        }
        float p = fmaxf(acc, 0.f) * sW2[lane];
        #pragma unroll
        for (int o = 32; o >= 1; o >>= 1) p += __shfl_xor(p, o, 64);
        if (lane == 0) out[row] = p + b2v;
    }
}

extern "C" void kernel_launch(void* const* d_in, const int* in_sizes, int n_in,
                              void* d_out, int out_size, void* d_ws, size_t ws_size,
                              hipStream_t stream) {
    const float* x   = (const float*)d_in[0];
    const int*   ei  = (const int*)d_in[1];
    const float* Wn0 = (const float*)d_in[2];
    const float* b0  = (const float*)d_in[3];
    const float* Wr0 = (const float*)d_in[4];
    const float* g0  = (const float*)d_in[5];
    const float* be0 = (const float*)d_in[6];
    const float* Wn1 = (const float*)d_in[7];
    const float* b1  = (const float*)d_in[8];
    const float* Wr1 = (const float*)d_in[9];
    const float* g1  = (const float*)d_in[10];
    const float* be1 = (const float*)d_in[11];
    const float* Wc1 = (const float*)d_in[12];
    const float* bc1 = (const float*)d_in[13];
    const float* Wc2 = (const float*)d_in[14];
    const float* bc2 = (const float*)d_in[15];
    float* out = (float*)d_out;

    const int N = in_sizes[0] / HID;
    const int E = in_sizes[1] / 2;
    const int* srcv = ei;
    const int* tgtv = ei + E;

    // workspace carve (256B aligned)
    size_t o = 0;
    auto carve = [&](size_t bytes) {
        void* p = (char*)d_ws + o;
        o += (bytes + 255) & ~(size_t)255;
        return p;
    };
    int* deg     = (int*)carve((size_t)N * 4);
    int* off     = (int*)carve((size_t)(N + 1) * 4);
    int* csr     = (int*)carve((size_t)E * 4);
    float* bufA  = (float*)carve((size_t)N * HID * 4);
    float* bufB  = (float*)carve((size_t)N * HID * 4);
    float* stats0  = (float*)carve(256 * 4);
    float* stats1  = (float*)carve(256 * 4);
    float* params0 = (float*)carve(256 * 4);
    float* params1 = (float*)carve(256 * 4);
    (void)ws_size; (void)n_in; (void)out_size;

    hipMemsetAsync(deg, 0, (size_t)N * 4, stream);
    hipMemsetAsync(stats0, 0, 256 * 4, stream);
    hipMemsetAsync(stats1, 0, 256 * 4, stream);

    int eblocks = (E + 255) / 256;
    hist_kernel<<<eblocks, 256, 0, stream>>>(tgtv, deg, E);
    scan_kernel<<<1, 1024, 0, stream>>>(deg, off, N);
    hipMemsetAsync(deg, 0, (size_t)N * 4, stream);
    fill_kernel<<<eblocks, 256, 0, stream>>>(srcv, tgtv, off, deg, csr, E);

    int aggblocks = (N * 64 + 255) / 256;
    float invn = 1.0f / (float)N;

    // layer 0
    aggregate_kernel<<<aggblocks, 256, 0, stream>>>(x, off, csr, bufA, N);
    sage_linear_kernel<<<256, 256, 0, stream>>>(bufA, x, Wn0, b0, Wr0, bufB, stats0, N);
    bnparam_kernel<<<1, 128, 0, stream>>>(stats0, g0, be0, params0, invn);
    norm_relu_kernel<<<aggblocks, 256, 0, stream>>>(bufB, params0, N * 64);

    // layer 1
    aggregate_kernel<<<aggblocks, 256, 0, stream>>>(bufB, off, csr, bufA, N);
    sage_linear_kernel<<<256, 256, 0, stream>>>(bufA, bufB, Wn1, b1, Wr1, bufA, stats1, N);
    bnparam_kernel<<<1, 128, 0, stream>>>(stats1, g1, be1, params1, invn);
    norm_relu_kernel<<<aggblocks, 256, 0, stream>>>(bufA, params1, N * 64);

    // classifier
    classifier_kernel<<<1024, 256, 0, stream>>>(bufA, Wc1, bc1, Wc2, bc2, out, N);
}

// Round 2
// 1500.795 us; speedup vs baseline: 1.0711x; 1.0711x over previous
//
#include <hip/hip_runtime.h>
#include <hip/hip_bf16.h>

// GraphSAGE 2-layer + BN + ReLU + MLP classifier, fp32 compute.
// R2 changes: (1) bf16 gather features (halve aggregate bytes; fp32 linear paths),
//             (2) parallel 3-phase scan replaces single-block scan.

#define HID 128
#define TILE_ROWS 16

__device__ inline uint32_t pack_bf16(float a, float b) {
    uint32_t ua = __float_as_uint(a);
    uint32_t ub = __float_as_uint(b);
    ua = ua + 0x7fffu + ((ua >> 16) & 1u);  // RNE
    ub = ub + 0x7fffu + ((ub >> 16) & 1u);
    return (ua >> 16) | (ub & 0xffff0000u);
}

__global__ void hist_kernel(const int* __restrict__ tgt, int* __restrict__ deg, int e) {
    int i = blockIdx.x * blockDim.x + threadIdx.x;
    if (i < e) atomicAdd(&deg[tgt[i]], 1);
}

// ---- parallel scan: partials -> scan partials -> final ----
__global__ void partial_sum_kernel(const int* __restrict__ deg, int* __restrict__ partials, int n) {
    __shared__ int ws[4];
    int base = blockIdx.x * 1024;
    int tid = threadIdx.x;
    int i = base + tid * 4;
    int s = 0;
    if (i + 3 < n) {
        int4 v = *(const int4*)(deg + i);
        s = v.x + v.y + v.z + v.w;
    } else {
        for (int k = 0; k < 4; ++k) if (i + k < n) s += deg[i + k];
    }
    #pragma unroll
    for (int o = 1; o < 64; o <<= 1) s += __shfl_xor(s, o, 64);
    if ((tid & 63) == 0) ws[tid >> 6] = s;
    __syncthreads();
    if (tid == 0) partials[blockIdx.x] = ws[0] + ws[1] + ws[2] + ws[3];
}

__global__ void scan_partials_kernel(int* __restrict__ partials, int np) {
    int lane = threadIdx.x;  // 64 threads
    int carry = 0;
    for (int base = 0; base < np; base += 64) {
        int i = base + lane;
        int v = (i < np) ? partials[i] : 0;
        int s = v;
        #pragma unroll
        for (int o = 1; o < 64; o <<= 1) {
            int t = __shfl_up(s, o, 64);
            if (lane >= o) s += t;
        }
        if (i < np) partials[i] = carry + s - v;  // exclusive
        carry += __shfl(s, 63, 64);
    }
}

__global__ void scan_final_kernel(const int* __restrict__ deg, const int* __restrict__ partials,
                                  int* __restrict__ off, int n, int e) {
    __shared__ int wsum[4];
    __shared__ int wpre[4];
    int base = blockIdx.x * 1024;
    int tid = threadIdx.x;
    int lane = tid & 63, wid = tid >> 6;
    int i = base + tid * 4;
    int v[4];
    #pragma unroll
    for (int k = 0; k < 4; ++k) v[k] = (i + k < n) ? deg[i + k] : 0;
    int tsum = v[0] + v[1] + v[2] + v[3];
    int s = tsum;
    #pragma unroll
    for (int o = 1; o < 64; o <<= 1) {
        int t = __shfl_up(s, o, 64);
        if (lane >= o) s += t;
    }
    if (lane == 63) wsum[wid] = s;
    __syncthreads();
    if (tid == 0) {
        int c = 0;
        #pragma unroll
        for (int w = 0; w < 4; ++w) { wpre[w] = c; c += wsum[w]; }
    }
    __syncthreads();
    int excl = partials[blockIdx.x] + wpre[wid] + (s - tsum);
    #pragma unroll
    for (int k = 0; k < 4; ++k) {
        if (i + k < n) off[i + k] = excl;
        excl += v[k];
    }
    if (blockIdx.x == 0 && tid == 0) off[n] = e;
}

__global__ void fill_kernel(const int* __restrict__ src, const int* __restrict__ tgt,
                            const int* __restrict__ off, int* __restrict__ cnt,
                            int* __restrict__ csr, int e) {
    int i = blockIdx.x * blockDim.x + threadIdx.x;
    if (i < e) {
        int t = tgt[i];
        int slot = off[t] + atomicAdd(&cnt[t], 1);
        csr[slot] = src[i];
    }
}

__global__ void f32_to_bf16_kernel(const float* __restrict__ in, uint32_t* __restrict__ out, int n2) {
    int i = blockIdx.x * blockDim.x + threadIdx.x;
    if (i < n2) {
        float2 v = ((const float2*)in)[i];
        out[i] = pack_bf16(v.x, v.y);
    }
}

// one wave per node: mean of bf16 neighbor rows (256B per row), fp32 accumulate
__global__ void aggregate_bf16_kernel(const uint32_t* __restrict__ feat, const int* __restrict__ off,
                                      const int* __restrict__ csr, float* __restrict__ outmean, int n) {
    int wv = (blockIdx.x * blockDim.x + threadIdx.x) >> 6;
    int lane = threadIdx.x & 63;
    if (wv >= n) return;
    int beg = off[wv], end = off[wv + 1];
    float2 acc = {0.f, 0.f};
    for (int j = beg; j < end; ++j) {
        int s = csr[j];
        uint32_t u = feat[(size_t)s * 64 + lane];
        acc.x += __uint_as_float(u << 16);
        acc.y += __uint_as_float(u & 0xffff0000u);
    }
    float inv = 1.0f / fmaxf((float)(end - beg), 1.0f);
    float2 m = {acc.x * inv, acc.y * inv};
    ((float2*)outmean)[(size_t)wv * 64 + lane] = m;
}

// h = mean @ Wn + b + x @ Wr ; accumulate per-column sum/sumsq into stats.
// Weights staged in LDS (128KB), 16-row input tiles in LDS. 4 rows/wave.
// Safe for hout == meanbuf (rows staged to LDS before overwrite).
__global__ __launch_bounds__(256, 1) void sage_linear_kernel(
    const float* __restrict__ meanbuf, const float* __restrict__ xbuf,
    const float* __restrict__ Wn, const float* __restrict__ bias,
    const float* __restrict__ Wr, float* __restrict__ hout,
    float* __restrict__ stats, int n) {
    __shared__ float sWn[HID * HID];
    __shared__ float sWr[HID * HID];
    __shared__ float sRow[2 * TILE_ROWS * HID];
    for (int i = threadIdx.x; i < HID * HID / 4; i += 256) {
        ((float4*)sWn)[i] = ((const float4*)Wn)[i];
        ((float4*)sWr)[i] = ((const float4*)Wr)[i];
    }
    int lane = threadIdx.x & 63;
    int wid = threadIdx.x >> 6;
    float2 bb = ((const float2*)bias)[lane];
    float2 ssum = {0.f, 0.f}, ssq = {0.f, 0.f};
    int ntiles = (n + TILE_ROWS - 1) / TILE_ROWS;
    for (int tile = blockIdx.x; tile < ntiles; tile += gridDim.x) {
        int row0 = tile * TILE_ROWS;
        int valid = min(TILE_ROWS, n - row0);
        int nvalid4 = valid * (HID / 4);
        __syncthreads();
        {
            const float4* msrc = (const float4*)(meanbuf + (size_t)row0 * HID);
            const float4* xsrc = (const float4*)(xbuf + (size_t)row0 * HID);
            float4* mdst = (float4*)sRow;
            float4* xdst = (float4*)(sRow + TILE_ROWS * HID);
            float4 z = {0.f, 0.f, 0.f, 0.f};
            for (int i = threadIdx.x; i < TILE_ROWS * HID / 4; i += 256) {
                mdst[i] = (i < nvalid4) ? msrc[i] : z;
                xdst[i] = (i < nvalid4) ? xsrc[i] : z;
            }
        }
        __syncthreads();
        float2 acc[4];
        #pragma unroll
        for (int r = 0; r < 4; ++r) acc[r] = bb;
        const float* mrow = sRow + (wid * 4) * HID;
        const float* xrow = sRow + TILE_ROWS * HID + (wid * 4) * HID;
        #pragma unroll 2
        for (int k = 0; k < HID; k += 4) {
            float4 m4[4], x4[4];
            #pragma unroll
            for (int r = 0; r < 4; ++r) {
                m4[r] = *(const float4*)(mrow + r * HID + k);
                x4[r] = *(const float4*)(xrow + r * HID + k);
            }
            #pragma unroll
            for (int kk = 0; kk < 4; ++kk) {
                float2 wn = *(const float2*)(sWn + (k + kk) * HID + 2 * lane);
                float2 wr = *(const float2*)(sWr + (k + kk) * HID + 2 * lane);
                #pragma unroll
                for (int r = 0; r < 4; ++r) {
                    float mv = ((const float*)&m4[r])[kk];
                    float xv = ((const float*)&x4[r])[kk];
                    acc[r].x = fmaf(mv, wn.x, acc[r].x);
                    acc[r].x = fmaf(xv, wr.x, acc[r].x);
                    acc[r].y = fmaf(mv, wn.y, acc[r].y);
                    acc[r].y = fmaf(xv, wr.y, acc[r].y);
                }
            }
        }
        #pragma unroll
        for (int r = 0; r < 4; ++r) {
            int lr = wid * 4 + r;
            if (lr < valid) {
                ((float2*)hout)[(size_t)(row0 + lr) * 64 + lane] = acc[r];
                ssum.x += acc[r].x; ssum.y += acc[r].y;
                ssq.x += acc[r].x * acc[r].x; ssq.y += acc[r].y * acc[r].y;
            }
        }
    }
    __syncthreads();
    float2* redS = (float2*)sRow;
    float2* redQ = ((float2*)sRow) + 256;
    redS[wid * 64 + lane] = ssum;
    redQ[wid * 64 + lane] = ssq;
    __syncthreads();
    if (wid == 0) {
        float2 ts = redS[lane], tq = redQ[lane];
        #pragma unroll
        for (int w = 1; w < 4; ++w) {
            ts.x += redS[w * 64 + lane].x; ts.y += redS[w * 64 + lane].y;
            tq.x += redQ[w * 64 + lane].x; tq.y += redQ[w * 64 + lane].y;
        }
        atomicAdd(&stats[2 * lane], ts.x);
        atomicAdd(&stats[2 * lane + 1], ts.y);
        atomicAdd(&stats[HID + 2 * lane], tq.x);
        atomicAdd(&stats[HID + 2 * lane + 1], tq.y);
    }
}

__global__ void bnparam_kernel(const float* __restrict__ stats, const float* __restrict__ g,
                               const float* __restrict__ be, float* __restrict__ params, float invn) {
    int j = threadIdx.x;  // 128
    float mu = stats[j] * invn;
    float var = stats[HID + j] * invn - mu * mu;
    float a = g[j] * rsqrtf(var + 1e-5f);
    params[j] = a;
    params[HID + j] = be[j] - mu * a;
}

// normalize+relu in place; optionally also write bf16 copy for the next gather
__global__ void norm_relu_kernel(float* __restrict__ h, uint32_t* __restrict__ hbf,
                                 const float* __restrict__ params, int total) {
    int i = blockIdx.x * blockDim.x + threadIdx.x;
    if (i >= total) return;
    int cp = i & 63;
    float a0 = params[2 * cp], a1 = params[2 * cp + 1];
    float b0 = params[HID + 2 * cp], b1 = params[HID + 2 * cp + 1];
    float2 v = ((float2*)h)[i];
    v.x = fmaxf(fmaf(v.x, a0, b0), 0.f);
    v.y = fmaxf(fmaf(v.y, a1, b1), 0.f);
    ((float2*)h)[i] = v;
    if (hbf) hbf[i] = pack_bf16(v.x, v.y);
}

// per-row: out = relu(hn @ Wc1 + bc1) @ Wc2 + bc2 ; one wave per row, Wc1 in LDS
__global__ __launch_bounds__(256) void classifier_kernel(
    const float* __restrict__ hn, const float* __restrict__ Wc1, const float* __restrict__ bc1,
    const float* __restrict__ Wc2, const float* __restrict__ bc2, float* __restrict__ out, int n) {
    __shared__ float sW[HID * 64];
    __shared__ float sW2[64];
    for (int i = threadIdx.x; i < HID * 64 / 4; i += 256) ((float4*)sW)[i] = ((const float4*)Wc1)[i];
    if (threadIdx.x < 64) sW2[threadIdx.x] = Wc2[threadIdx.x];
    __syncthreads();
    int lane = threadIdx.x & 63;
    float b1v = bc1[lane];
    float b2v = bc2[0];
    int nwaves = (gridDim.x * blockDim.x) >> 6;
    int gw = (blockIdx.x * blockDim.x + threadIdx.x) >> 6;
    for (int row = gw; row < n; row += nwaves) {
        float2 hv = ((const float2*)hn)[(size_t)row * 64 + lane];
        float acc = b1v;
        #pragma unroll
        for (int k2 = 0; k2 < 64; ++k2) {
            float hx = __shfl(hv.x, k2, 64);
            float hy = __shfl(hv.y, k2, 64);
            acc = fmaf(hx, sW[(2 * k2) * 64 + lane], acc);
            acc = fmaf(hy, sW[(2 * k2 + 1) * 64 + lane], acc);
        }
        float p = fmaxf(acc, 0.f) * sW2[lane];
        #pragma unroll
        for (int o = 32; o >= 1; o >>= 1) p += __shfl_xor(p, o, 64);
        if (lane == 0) out[row] = p + b2v;
    }
}

extern "C" void kernel_launch(void* const* d_in, const int* in_sizes, int n_in,
                              void* d_out, int out_size, void* d_ws, size_t ws_size,
                              hipStream_t stream) {
    const float* x   = (const float*)d_in[0];
    const int*   ei  = (const int*)d_in[1];
    const float* Wn0 = (const float*)d_in[2];
    const float* b0  = (const float*)d_in[3];
    const float* Wr0 = (const float*)d_in[4];
    const float* g0  = (const float*)d_in[5];
    const float* be0 = (const float*)d_in[6];
    const float* Wn1 = (const float*)d_in[7];
    const float* b1  = (const float*)d_in[8];
    const float* Wr1 = (const float*)d_in[9];
    const float* g1  = (const float*)d_in[10];
    const float* be1 = (const float*)d_in[11];
    const float* Wc1 = (const float*)d_in[12];
    const float* bc1 = (const float*)d_in[13];
    const float* Wc2 = (const float*)d_in[14];
    const float* bc2 = (const float*)d_in[15];
    float* out = (float*)d_out;

    const int N = in_sizes[0] / HID;
    const int E = in_sizes[1] / 2;
    const int* srcv = ei;
    const int* tgtv = ei + E;

    size_t o = 0;
    auto carve = [&](size_t bytes) {
        void* p = (char*)d_ws + o;
        o += (bytes + 255) & ~(size_t)255;
        return p;
    };
    int* deg       = (int*)carve((size_t)N * 4);
    int* off       = (int*)carve((size_t)(N + 1) * 4);
    int* csr       = (int*)carve((size_t)E * 4);
    float* bufA    = (float*)carve((size_t)N * HID * 4);
    float* bufB    = (float*)carve((size_t)N * HID * 4);
    uint32_t* fbf  = (uint32_t*)carve((size_t)N * HID * 2);  // bf16 gather features (x, then h0)
    int* partials  = (int*)carve(1024 * 4);
    float* stats0  = (float*)carve(256 * 4);
    float* stats1  = (float*)carve(256 * 4);
    float* params0 = (float*)carve(256 * 4);
    float* params1 = (float*)carve(256 * 4);
    (void)ws_size; (void)n_in; (void)out_size;

    hipMemsetAsync(deg, 0, (size_t)N * 4, stream);
    hipMemsetAsync(stats0, 0, 256 * 4, stream);
    hipMemsetAsync(stats1, 0, 256 * 4, stream);

    int eblocks = (E + 255) / 256;
    int nparts = (N + 1023) / 1024;

    hist_kernel<<<eblocks, 256, 0, stream>>>(tgtv, deg, E);
    partial_sum_kernel<<<nparts, 256, 0, stream>>>(deg, partials, N);
    scan_partials_kernel<<<1, 64, 0, stream>>>(partials, nparts);
    scan_final_kernel<<<nparts, 256, 0, stream>>>(deg, partials, off, N, E);
    hipMemsetAsync(deg, 0, (size_t)N * 4, stream);
    fill_kernel<<<eblocks, 256, 0, stream>>>(srcv, tgtv, off, deg, csr, E);

    int aggblocks = (N * 64 + 255) / 256;
    int cvtblocks = (N * 64 + 255) / 256;
    float invn = 1.0f / (float)N;

    // layer 0
    f32_to_bf16_kernel<<<cvtblocks, 256, 0, stream>>>(x, fbf, N * 64);
    aggregate_bf16_kernel<<<aggblocks, 256, 0, stream>>>(fbf, off, csr, bufA, N);
    sage_linear_kernel<<<256, 256, 0, stream>>>(bufA, x, Wn0, b0, Wr0, bufB, stats0, N);
    bnparam_kernel<<<1, 128, 0, stream>>>(stats0, g0, be0, params0, invn);
    norm_relu_kernel<<<aggblocks, 256, 0, stream>>>(bufB, fbf, params0, N * 64);  // dual write: fp32 + bf16

    // layer 1
    aggregate_bf16_kernel<<<aggblocks, 256, 0, stream>>>(fbf, off, csr, bufA, N);
    sage_linear_kernel<<<256, 256, 0, stream>>>(bufA, bufB, Wn1, b1, Wr1, bufA, stats1, N);
    bnparam_kernel<<<1, 128, 0, stream>>>(stats1, g1, be1, params1, invn);
    norm_relu_kernel<<<aggblocks, 256, 0, stream>>>(bufA, nullptr, params1, N * 64);

    // classifier
    classifier_kernel<<<1024, 256, 0, stream>>>(bufA, Wc1, bc1, Wc2, bc2, out, N);
}

// Round 4
// 1167.702 us; speedup vs baseline: 1.3767x; 1.2853x over previous
//
#include <hip/hip_runtime.h>
#include <hip/hip_bf16.h>

// GraphSAGE 2-layer + BN + ReLU + MLP classifier, fp32 compute.
// R4: fixes R3's divergent-__shfl bug in aggregate (uniform broadcast loop,
//     predicated load/acc). Keeps 4-edges/iter dwordx4 gather structure.

#define HID 128
#define TILE_ROWS 16

__device__ inline uint32_t pack_bf16(float a, float b) {
    uint32_t ua = __float_as_uint(a);
    uint32_t ub = __float_as_uint(b);
    ua = ua + 0x7fffu + ((ua >> 16) & 1u);  // RNE
    ub = ub + 0x7fffu + ((ub >> 16) & 1u);
    return (ua >> 16) | (ub & 0xffff0000u);
}

__global__ void hist_kernel(const int* __restrict__ tgt, int* __restrict__ deg, int e) {
    int i = blockIdx.x * blockDim.x + threadIdx.x;
    if (i < e) atomicAdd(&deg[tgt[i]], 1);
}

// ---- parallel scan: partials -> scan partials -> final ----
__global__ void partial_sum_kernel(const int* __restrict__ deg, int* __restrict__ partials, int n) {
    __shared__ int ws[4];
    int base = blockIdx.x * 1024;
    int tid = threadIdx.x;
    int i = base + tid * 4;
    int s = 0;
    if (i + 3 < n) {
        int4 v = *(const int4*)(deg + i);
        s = v.x + v.y + v.z + v.w;
    } else {
        for (int k = 0; k < 4; ++k) if (i + k < n) s += deg[i + k];
    }
    #pragma unroll
    for (int o = 1; o < 64; o <<= 1) s += __shfl_xor(s, o, 64);
    if ((tid & 63) == 0) ws[tid >> 6] = s;
    __syncthreads();
    if (tid == 0) partials[blockIdx.x] = ws[0] + ws[1] + ws[2] + ws[3];
}

__global__ void scan_partials_kernel(int* __restrict__ partials, int np) {
    int lane = threadIdx.x;  // 64 threads
    int carry = 0;
    for (int base = 0; base < np; base += 64) {
        int i = base + lane;
        int v = (i < np) ? partials[i] : 0;
        int s = v;
        #pragma unroll
        for (int o = 1; o < 64; o <<= 1) {
            int t = __shfl_up(s, o, 64);
            if (lane >= o) s += t;
        }
        if (i < np) partials[i] = carry + s - v;  // exclusive
        carry += __shfl(s, 63, 64);
    }
}

__global__ void scan_final_kernel(const int* __restrict__ deg, const int* __restrict__ partials,
                                  int* __restrict__ off, int n, int e) {
    __shared__ int wsum[4];
    __shared__ int wpre[4];
    int base = blockIdx.x * 1024;
    int tid = threadIdx.x;
    int lane = tid & 63, wid = tid >> 6;
    int i = base + tid * 4;
    int v[4];
    #pragma unroll
    for (int k = 0; k < 4; ++k) v[k] = (i + k < n) ? deg[i + k] : 0;
    int tsum = v[0] + v[1] + v[2] + v[3];
    int s = tsum;
    #pragma unroll
    for (int o = 1; o < 64; o <<= 1) {
        int t = __shfl_up(s, o, 64);
        if (lane >= o) s += t;
    }
    if (lane == 63) wsum[wid] = s;
    __syncthreads();
    if (tid == 0) {
        int c = 0;
        #pragma unroll
        for (int w = 0; w < 4; ++w) { wpre[w] = c; c += wsum[w]; }
    }
    __syncthreads();
    int excl = partials[blockIdx.x] + wpre[wid] + (s - tsum);
    #pragma unroll
    for (int k = 0; k < 4; ++k) {
        if (i + k < n) off[i + k] = excl;
        excl += v[k];
    }
    if (blockIdx.x == 0 && tid == 0) off[n] = e;
}

__global__ void fill_kernel(const int* __restrict__ src, const int* __restrict__ tgt,
                            const int* __restrict__ off, int* __restrict__ cnt,
                            int* __restrict__ csr, int e) {
    int i = blockIdx.x * blockDim.x + threadIdx.x;
    if (i < e) {
        int t = tgt[i];
        int slot = off[t] + atomicAdd(&cnt[t], 1);
        csr[slot] = src[i];
    }
}

__global__ void f32_to_bf16_kernel(const float* __restrict__ in, uint32_t* __restrict__ out, int n2) {
    int i = blockIdx.x * blockDim.x + threadIdx.x;
    if (i < n2) {
        float2 v = ((const float2*)in)[i];
        out[i] = pack_bf16(v.x, v.y);
    }
}

// one wave per node; 4 edges per iteration. 16 lanes cover one 256B bf16 row
// with dwordx4 loads; CSR indices preloaded 64-at-a-time, broadcast via __shfl.
// NOTE: the broadcast loop is wave-UNIFORM (j0 steps for all lanes); only the
// load+accumulate is predicated — __shfl always runs with all 64 lanes active.
__global__ __launch_bounds__(256) void aggregate_bf16_kernel(
    const uint32_t* __restrict__ feat, const int* __restrict__ off,
    const int* __restrict__ csr, float* __restrict__ outmean, int n) {
    int wv = (blockIdx.x * blockDim.x + threadIdx.x) >> 6;
    int lane = threadIdx.x & 63;
    if (wv >= n) return;
    int beg = off[wv], end = off[wv + 1];
    int len = end - beg;
    int sub = lane >> 4;   // which of 4 concurrent edges
    int c   = lane & 15;   // dword-group: dwords c*4..c*4+3 = bf16 cols c*8..c*8+7
    float acc[8];
    #pragma unroll
    for (int k = 0; k < 8; ++k) acc[k] = 0.f;
    for (int base = 0; base < len; base += 64) {
        int m = len - base; if (m > 64) m = 64;
        int idx = csr[beg + base + (lane < m ? lane : 0)];
        for (int j0 = 0; j0 < m; j0 += 4) {           // wave-uniform trip count
            int j = j0 + sub;
            int s = __shfl(idx, (j < m ? j : 0), 64); // all lanes active here
            if (j < m) {
                uint4 u = *(const uint4*)(feat + (size_t)s * 64 + c * 4);
                acc[0] += __uint_as_float(u.x << 16);
                acc[1] += __uint_as_float(u.x & 0xffff0000u);
                acc[2] += __uint_as_float(u.y << 16);
                acc[3] += __uint_as_float(u.y & 0xffff0000u);
                acc[4] += __uint_as_float(u.z << 16);
                acc[5] += __uint_as_float(u.z & 0xffff0000u);
                acc[6] += __uint_as_float(u.w << 16);
                acc[7] += __uint_as_float(u.w & 0xffff0000u);
            }
        }
    }
    #pragma unroll
    for (int k = 0; k < 8; ++k) {
        acc[k] += __shfl_xor(acc[k], 16, 64);
        acc[k] += __shfl_xor(acc[k], 32, 64);
    }
    float inv = 1.0f / fmaxf((float)len, 1.0f);
    float2 w2 = { acc[sub * 2] * inv, acc[sub * 2 + 1] * inv };
    ((float2*)outmean)[(size_t)wv * 64 + c * 4 + sub] = w2;
}

// h = mean @ Wn + b + x @ Wr ; accumulate per-column sum/sumsq into stats.
// Weights staged in LDS (128KB), 16-row input tiles in LDS. 4 rows/wave.
// Safe for hout == meanbuf (rows staged to LDS before overwrite).
__global__ __launch_bounds__(256, 1) void sage_linear_kernel(
    const float* __restrict__ meanbuf, const float* __restrict__ xbuf,
    const float* __restrict__ Wn, const float* __restrict__ bias,
    const float* __restrict__ Wr, float* __restrict__ hout,
    float* __restrict__ stats, int n) {
    __shared__ float sWn[HID * HID];
    __shared__ float sWr[HID * HID];
    __shared__ float sRow[2 * TILE_ROWS * HID];
    for (int i = threadIdx.x; i < HID * HID / 4; i += 256) {
        ((float4*)sWn)[i] = ((const float4*)Wn)[i];
        ((float4*)sWr)[i] = ((const float4*)Wr)[i];
    }
    int lane = threadIdx.x & 63;
    int wid = threadIdx.x >> 6;
    float2 bb = ((const float2*)bias)[lane];
    float2 ssum = {0.f, 0.f}, ssq = {0.f, 0.f};
    int ntiles = (n + TILE_ROWS - 1) / TILE_ROWS;
    for (int tile = blockIdx.x; tile < ntiles; tile += gridDim.x) {
        int row0 = tile * TILE_ROWS;
        int valid = min(TILE_ROWS, n - row0);
        int nvalid4 = valid * (HID / 4);
        __syncthreads();
        {
            const float4* msrc = (const float4*)(meanbuf + (size_t)row0 * HID);
            const float4* xsrc = (const float4*)(xbuf + (size_t)row0 * HID);
            float4* mdst = (float4*)sRow;
            float4* xdst = (float4*)(sRow + TILE_ROWS * HID);
            float4 z = {0.f, 0.f, 0.f, 0.f};
            for (int i = threadIdx.x; i < TILE_ROWS * HID / 4; i += 256) {
                mdst[i] = (i < nvalid4) ? msrc[i] : z;
                xdst[i] = (i < nvalid4) ? xsrc[i] : z;
            }
        }
        __syncthreads();
        float2 acc[4];
        #pragma unroll
        for (int r = 0; r < 4; ++r) acc[r] = bb;
        const float* mrow = sRow + (wid * 4) * HID;
        const float* xrow = sRow + TILE_ROWS * HID + (wid * 4) * HID;
        #pragma unroll 2
        for (int k = 0; k < HID; k += 4) {
            float4 m4[4], x4[4];
            #pragma unroll
            for (int r = 0; r < 4; ++r) {
                m4[r] = *(const float4*)(mrow + r * HID + k);
                x4[r] = *(const float4*)(xrow + r * HID + k);
            }
            #pragma unroll
            for (int kk = 0; kk < 4; ++kk) {
                float2 wn = *(const float2*)(sWn + (k + kk) * HID + 2 * lane);
                float2 wr = *(const float2*)(sWr + (k + kk) * HID + 2 * lane);
                #pragma unroll
                for (int r = 0; r < 4; ++r) {
                    float mv = ((const float*)&m4[r])[kk];
                    float xv = ((const float*)&x4[r])[kk];
                    acc[r].x = fmaf(mv, wn.x, acc[r].x);
                    acc[r].x = fmaf(xv, wr.x, acc[r].x);
                    acc[r].y = fmaf(mv, wn.y, acc[r].y);
                    acc[r].y = fmaf(xv, wr.y, acc[r].y);
                }
            }
        }
        #pragma unroll
        for (int r = 0; r < 4; ++r) {
            int lr = wid * 4 + r;
            if (lr < valid) {
                ((float2*)hout)[(size_t)(row0 + lr) * 64 + lane] = acc[r];
                ssum.x += acc[r].x; ssum.y += acc[r].y;
                ssq.x += acc[r].x * acc[r].x; ssq.y += acc[r].y * acc[r].y;
            }
        }
    }
    __syncthreads();
    float2* redS = (float2*)sRow;
    float2* redQ = ((float2*)sRow) + 256;
    redS[wid * 64 + lane] = ssum;
    redQ[wid * 64 + lane] = ssq;
    __syncthreads();
    if (wid == 0) {
        float2 ts = redS[lane], tq = redQ[lane];
        #pragma unroll
        for (int w = 1; w < 4; ++w) {
            ts.x += redS[w * 64 + lane].x; ts.y += redS[w * 64 + lane].y;
            tq.x += redQ[w * 64 + lane].x; tq.y += redQ[w * 64 + lane].y;
        }
        atomicAdd(&stats[2 * lane], ts.x);
        atomicAdd(&stats[2 * lane + 1], ts.y);
        atomicAdd(&stats[HID + 2 * lane], tq.x);
        atomicAdd(&stats[HID + 2 * lane + 1], tq.y);
    }
}

__global__ void bnparam_kernel(const float* __restrict__ stats, const float* __restrict__ g,
                               const float* __restrict__ be, float* __restrict__ params, float invn) {
    int j = threadIdx.x;  // 128
    float mu = stats[j] * invn;
    float var = stats[HID + j] * invn - mu * mu;
    float a = g[j] * rsqrtf(var + 1e-5f);
    params[j] = a;
    params[HID + j] = be[j] - mu * a;
}

// normalize+relu in place; optionally also write bf16 copy for the next gather
__global__ void norm_relu_kernel(float* __restrict__ h, uint32_t* __restrict__ hbf,
                                 const float* __restrict__ params, int total) {
    int i = blockIdx.x * blockDim.x + threadIdx.x;
    if (i >= total) return;
    int cp = i & 63;
    float a0 = params[2 * cp], a1 = params[2 * cp + 1];
    float b0 = params[HID + 2 * cp], b1 = params[HID + 2 * cp + 1];
    float2 v = ((float2*)h)[i];
    v.x = fmaxf(fmaf(v.x, a0, b0), 0.f);
    v.y = fmaxf(fmaf(v.y, a1, b1), 0.f);
    ((float2*)h)[i] = v;
    if (hbf) hbf[i] = pack_bf16(v.x, v.y);
}

// per-row: out = relu(hn @ Wc1 + bc1) @ Wc2 + bc2 ; one wave per row, Wc1 in LDS
__global__ __launch_bounds__(256) void classifier_kernel(
    const float* __restrict__ hn, const float* __restrict__ Wc1, const float* __restrict__ bc1,
    const float* __restrict__ Wc2, const float* __restrict__ bc2, float* __restrict__ out, int n) {
    __shared__ float sW[HID * 64];
    __shared__ float sW2[64];
    for (int i = threadIdx.x; i < HID * 64 / 4; i += 256) ((float4*)sW)[i] = ((const float4*)Wc1)[i];
    if (threadIdx.x < 64) sW2[threadIdx.x] = Wc2[threadIdx.x];
    __syncthreads();
    int lane = threadIdx.x & 63;
    float b1v = bc1[lane];
    float b2v = bc2[0];
    int nwaves = (gridDim.x * blockDim.x) >> 6;
    int gw = (blockIdx.x * blockDim.x + threadIdx.x) >> 6;
    for (int row = gw; row < n; row += nwaves) {
        float2 hv = ((const float2*)hn)[(size_t)row * 64 + lane];
        float acc = b1v;
        #pragma unroll
        for (int k2 = 0; k2 < 64; ++k2) {
            float hx = __shfl(hv.x, k2, 64);
            float hy = __shfl(hv.y, k2, 64);
            acc = fmaf(hx, sW[(2 * k2) * 64 + lane], acc);
            acc = fmaf(hy, sW[(2 * k2 + 1) * 64 + lane], acc);
        }
        float p = fmaxf(acc, 0.f) * sW2[lane];
        #pragma unroll
        for (int o = 32; o >= 1; o >>= 1) p += __shfl_xor(p, o, 64);
        if (lane == 0) out[row] = p + b2v;
    }
}

extern "C" void kernel_launch(void* const* d_in, const int* in_sizes, int n_in,
                              void* d_out, int out_size, void* d_ws, size_t ws_size,
                              hipStream_t stream) {
    const float* x   = (const float*)d_in[0];
    const int*   ei  = (const int*)d_in[1];
    const float* Wn0 = (const float*)d_in[2];
    const float* b0  = (const float*)d_in[3];
    const float* Wr0 = (const float*)d_in[4];
    const float* g0  = (const float*)d_in[5];
    const float* be0 = (const float*)d_in[6];
    const float* Wn1 = (const float*)d_in[7];
    const float* b1  = (const float*)d_in[8];
    const float* Wr1 = (const float*)d_in[9];
    const float* g1  = (const float*)d_in[10];
    const float* be1 = (const float*)d_in[11];
    const float* Wc1 = (const float*)d_in[12];
    const float* bc1 = (const float*)d_in[13];
    const float* Wc2 = (const float*)d_in[14];
    const float* bc2 = (const float*)d_in[15];
    float* out = (float*)d_out;

    const int N = in_sizes[0] / HID;
    const int E = in_sizes[1] / 2;
    const int* srcv = ei;
    const int* tgtv = ei + E;

    size_t o = 0;
    auto carve = [&](size_t bytes) {
        void* p = (char*)d_ws + o;
        o += (bytes + 255) & ~(size_t)255;
        return p;
    };
    int* deg       = (int*)carve((size_t)N * 4);
    int* off       = (int*)carve((size_t)(N + 1) * 4);
    int* csr       = (int*)carve((size_t)E * 4);
    float* bufA    = (float*)carve((size_t)N * HID * 4);
    float* bufB    = (float*)carve((size_t)N * HID * 4);
    uint32_t* fbf  = (uint32_t*)carve((size_t)N * HID * 2);  // bf16 gather features (x, then h0)
    int* partials  = (int*)carve(1024 * 4);
    float* stats0  = (float*)carve(256 * 4);
    float* stats1  = (float*)carve(256 * 4);
    float* params0 = (float*)carve(256 * 4);
    float* params1 = (float*)carve(256 * 4);
    (void)ws_size; (void)n_in; (void)out_size;

    hipMemsetAsync(deg, 0, (size_t)N * 4, stream);
    hipMemsetAsync(stats0, 0, 256 * 4, stream);
    hipMemsetAsync(stats1, 0, 256 * 4, stream);

    int eblocks = (E + 255) / 256;
    int nparts = (N + 1023) / 1024;

    hist_kernel<<<eblocks, 256, 0, stream>>>(tgtv, deg, E);
    partial_sum_kernel<<<nparts, 256, 0, stream>>>(deg, partials, N);
    scan_partials_kernel<<<1, 64, 0, stream>>>(partials, nparts);
    scan_final_kernel<<<nparts, 256, 0, stream>>>(deg, partials, off, N, E);
    hipMemsetAsync(deg, 0, (size_t)N * 4, stream);
    fill_kernel<<<eblocks, 256, 0, stream>>>(srcv, tgtv, off, deg, csr, E);

    int aggblocks = (N * 64 + 255) / 256;
    int cvtblocks = (N * 64 + 255) / 256;
    float invn = 1.0f / (float)N;

    // layer 0
    f32_to_bf16_kernel<<<cvtblocks, 256, 0, stream>>>(x, fbf, N * 64);
    aggregate_bf16_kernel<<<aggblocks, 256, 0, stream>>>(fbf, off, csr, bufA, N);
    sage_linear_kernel<<<256, 256, 0, stream>>>(bufA, x, Wn0, b0, Wr0, bufB, stats0, N);
    bnparam_kernel<<<1, 128, 0, stream>>>(stats0, g0, be0, params0, invn);
    norm_relu_kernel<<<aggblocks, 256, 0, stream>>>(bufB, fbf, params0, N * 64);  // dual write: fp32 + bf16

    // layer 1
    aggregate_bf16_kernel<<<aggblocks, 256, 0, stream>>>(fbf, off, csr, bufA, N);
    sage_linear_kernel<<<256, 256, 0, stream>>>(bufA, bufB, Wn1, b1, Wr1, bufA, stats1, N);
    bnparam_kernel<<<1, 128, 0, stream>>>(stats1, g1, be1, params1, invn);
    norm_relu_kernel<<<aggblocks, 256, 0, stream>>>(bufA, nullptr, params1, N * 64);

    // classifier
    classifier_kernel<<<1024, 256, 0, stream>>>(bufA, Wc1, bc1, Wc2, bc2, out, N);
}

// Round 5
// 822.436 us; speedup vs baseline: 1.9546x; 1.4198x over previous
//
#include <hip/hip_runtime.h>
#include <hip/hip_bf16.h>

// GraphSAGE 2-layer + BN + ReLU + MLP classifier.
// R5: sage linear -> MFMA bf16 (fused K=256 GEMM [mean|x]@[Wn;Wr]+b with
//     in-register BN stats). Aggregate emits bf16 mean directly.

#define HID 128

typedef __attribute__((ext_vector_type(8))) short short8;
typedef __attribute__((ext_vector_type(4))) float f32x4;

union FragU { uint4 u; short8 s; };

__device__ inline uint32_t pack_bf16(float a, float b) {
    uint32_t ua = __float_as_uint(a);
    uint32_t ub = __float_as_uint(b);
    ua = ua + 0x7fffu + ((ua >> 16) & 1u);  // RNE
    ub = ub + 0x7fffu + ((ub >> 16) & 1u);
    return (ua >> 16) | (ub & 0xffff0000u);
}

__global__ void hist_kernel(const int* __restrict__ tgt, int* __restrict__ deg, int e) {
    int i = blockIdx.x * blockDim.x + threadIdx.x;
    if (i < e) atomicAdd(&deg[tgt[i]], 1);
}

// ---- parallel scan: partials -> scan partials -> final ----
__global__ void partial_sum_kernel(const int* __restrict__ deg, int* __restrict__ partials, int n) {
    __shared__ int ws[4];
    int base = blockIdx.x * 1024;
    int tid = threadIdx.x;
    int i = base + tid * 4;
    int s = 0;
    if (i + 3 < n) {
        int4 v = *(const int4*)(deg + i);
        s = v.x + v.y + v.z + v.w;
    } else {
        for (int k = 0; k < 4; ++k) if (i + k < n) s += deg[i + k];
    }
    #pragma unroll
    for (int o = 1; o < 64; o <<= 1) s += __shfl_xor(s, o, 64);
    if ((tid & 63) == 0) ws[tid >> 6] = s;
    __syncthreads();
    if (tid == 0) partials[blockIdx.x] = ws[0] + ws[1] + ws[2] + ws[3];
}

__global__ void scan_partials_kernel(int* __restrict__ partials, int np) {
    int lane = threadIdx.x;  // 64 threads
    int carry = 0;
    for (int base = 0; base < np; base += 64) {
        int i = base + lane;
        int v = (i < np) ? partials[i] : 0;
        int s = v;
        #pragma unroll
        for (int o = 1; o < 64; o <<= 1) {
            int t = __shfl_up(s, o, 64);
            if (lane >= o) s += t;
        }
        if (i < np) partials[i] = carry + s - v;  // exclusive
        carry += __shfl(s, 63, 64);
    }
}

__global__ void scan_final_kernel(const int* __restrict__ deg, const int* __restrict__ partials,
                                  int* __restrict__ off, int n, int e) {
    __shared__ int wsum[4];
    __shared__ int wpre[4];
    int base = blockIdx.x * 1024;
    int tid = threadIdx.x;
    int lane = tid & 63, wid = tid >> 6;
    int i = base + tid * 4;
    int v[4];
    #pragma unroll
    for (int k = 0; k < 4; ++k) v[k] = (i + k < n) ? deg[i + k] : 0;
    int tsum = v[0] + v[1] + v[2] + v[3];
    int s = tsum;
    #pragma unroll
    for (int o = 1; o < 64; o <<= 1) {
        int t = __shfl_up(s, o, 64);
        if (lane >= o) s += t;
    }
    if (lane == 63) wsum[wid] = s;
    __syncthreads();
    if (tid == 0) {
        int c = 0;
        #pragma unroll
        for (int w = 0; w < 4; ++w) { wpre[w] = c; c += wsum[w]; }
    }
    __syncthreads();
    int excl = partials[blockIdx.x] + wpre[wid] + (s - tsum);
    #pragma unroll
    for (int k = 0; k < 4; ++k) {
        if (i + k < n) off[i + k] = excl;
        excl += v[k];
    }
    if (blockIdx.x == 0 && tid == 0) off[n] = e;
}

__global__ void fill_kernel(const int* __restrict__ src, const int* __restrict__ tgt,
                            const int* __restrict__ off, int* __restrict__ cnt,
                            int* __restrict__ csr, int e) {
    int i = blockIdx.x * blockDim.x + threadIdx.x;
    if (i < e) {
        int t = tgt[i];
        int slot = off[t] + atomicAdd(&cnt[t], 1);
        csr[slot] = src[i];
    }
}

__global__ void f32_to_bf16_kernel(const float* __restrict__ in, uint32_t* __restrict__ out, int n2) {
    int i = blockIdx.x * blockDim.x + threadIdx.x;
    if (i < n2) {
        float2 v = ((const float2*)in)[i];
        out[i] = pack_bf16(v.x, v.y);
    }
}

// Pack [Wn;Wr] (two 128x128 row-major f32, W[k][n]) into MFMA B-frag bf16 layout:
// packed16B[(ko*8+no)*64 + lane] = 8 bf16: W[ko*32+(lane>>4)*8+j][no*16+(lane&15)]
__global__ void pack_w_kernel(const float* __restrict__ Wn, const float* __restrict__ Wr,
                              uint32_t* __restrict__ packed) {
    int t = blockIdx.x * blockDim.x + threadIdx.x;  // 4096 threads
    if (t >= 4096) return;
    int lane = t & 63;
    int no = (t >> 6) & 7;
    int ko = t >> 9;
    int n = no * 16 + (lane & 15);
    int kbase = ko * 32 + ((lane >> 4) << 3);
    uint32_t v[4];
    #pragma unroll
    for (int jj = 0; jj < 4; ++jj) {
        int k0 = kbase + jj * 2, k1 = k0 + 1;
        float a = (k0 < 128) ? Wn[k0 * 128 + n] : Wr[(k0 - 128) * 128 + n];
        float b = (k1 < 128) ? Wn[k1 * 128 + n] : Wr[(k1 - 128) * 128 + n];
        v[jj] = pack_bf16(a, b);
    }
    uint4 u4; u4.x = v[0]; u4.y = v[1]; u4.z = v[2]; u4.w = v[3];
    ((uint4*)packed)[t] = u4;
}

// one wave per node; 4 edges/iter, dwordx4, wave-uniform __shfl broadcast.
// Output: bf16 mean row (64 uint32 per node).
__global__ __launch_bounds__(256) void aggregate_bf16_kernel(
    const uint32_t* __restrict__ feat, const int* __restrict__ off,
    const int* __restrict__ csr, uint32_t* __restrict__ outmean, int n) {
    int wv = (blockIdx.x * blockDim.x + threadIdx.x) >> 6;
    int lane = threadIdx.x & 63;
    if (wv >= n) return;
    int beg = off[wv], end = off[wv + 1];
    int len = end - beg;
    int sub = lane >> 4;
    int c   = lane & 15;
    float acc[8];
    #pragma unroll
    for (int k = 0; k < 8; ++k) acc[k] = 0.f;
    for (int base = 0; base < len; base += 64) {
        int m = len - base; if (m > 64) m = 64;
        int idx = csr[beg + base + (lane < m ? lane : 0)];
        for (int j0 = 0; j0 < m; j0 += 4) {           // wave-uniform trip count
            int j = j0 + sub;
            int s = __shfl(idx, (j < m ? j : 0), 64); // all lanes active
            if (j < m) {
                uint4 u = *(const uint4*)(feat + (size_t)s * 64 + c * 4);
                acc[0] += __uint_as_float(u.x << 16);
                acc[1] += __uint_as_float(u.x & 0xffff0000u);
                acc[2] += __uint_as_float(u.y << 16);
                acc[3] += __uint_as_float(u.y & 0xffff0000u);
                acc[4] += __uint_as_float(u.z << 16);
                acc[5] += __uint_as_float(u.z & 0xffff0000u);
                acc[6] += __uint_as_float(u.w << 16);
                acc[7] += __uint_as_float(u.w & 0xffff0000u);
            }
        }
    }
    #pragma unroll
    for (int k = 0; k < 8; ++k) {
        acc[k] += __shfl_xor(acc[k], 16, 64);
        acc[k] += __shfl_xor(acc[k], 32, 64);
    }
    float inv = 1.0f / fmaxf((float)len, 1.0f);
    outmean[(size_t)wv * 64 + c * 4 + sub] = pack_bf16(acc[sub * 2] * inv, acc[sub * 2 + 1] * inv);
}

// h = [mean|x](bf16) @ Wpacked(256x128 bf16) + b via 16x16x32 bf16 MFMA.
// Each wave: one 16-row strip, full 128 cols (8 n-tiles), K=256 (8 k-tiles).
// Also accumulates per-column sum/sumsq -> stats (atomics per block).
__global__ __launch_bounds__(256) void sage_mfma_kernel(
    const uint32_t* __restrict__ meanbf, const uint32_t* __restrict__ xbf,
    const uint32_t* __restrict__ Wp, const float* __restrict__ bias,
    float* __restrict__ hout, float* __restrict__ stats, int n) {
    __shared__ uint4 sW[4096];          // 64 KB packed weights
    __shared__ float redS[4][128];
    __shared__ float redQ[4][128];
    for (int i = threadIdx.x; i < 4096; i += 256) sW[i] = ((const uint4*)Wp)[i];
    __syncthreads();
    int lane = threadIdx.x & 63;
    int wid = threadIdx.x >> 6;
    int c = lane & 15;     // A row within strip / C col within n-tile
    int kg = lane >> 4;    // k-group / C row-group
    float bcol[8];
    #pragma unroll
    for (int no = 0; no < 8; ++no) bcol[no] = bias[no * 16 + c];
    float ssum[8], ssq[8];
    #pragma unroll
    for (int no = 0; no < 8; ++no) { ssum[no] = 0.f; ssq[no] = 0.f; }
    int nstrips = n >> 4;  // n % 16 == 0 (N=100000)
    int sstride = gridDim.x * 4;
    for (int strip = blockIdx.x * 4 + wid; strip < nstrips; strip += sstride) {
        const uint4* mrow = (const uint4*)(meanbf + (size_t)(strip * 16 + c) * 64);
        const uint4* xrow = (const uint4*)(xbf + (size_t)(strip * 16 + c) * 64);
        f32x4 acc[8];
        #pragma unroll
        for (int no = 0; no < 8; ++no) acc[no] = (f32x4){0.f, 0.f, 0.f, 0.f};
        #pragma unroll
        for (int ko = 0; ko < 8; ++ko) {
            FragU a;
            a.u = (ko < 4) ? mrow[ko * 4 + kg] : xrow[(ko - 4) * 4 + kg];
            #pragma unroll
            for (int no = 0; no < 8; ++no) {
                FragU b;
                b.u = sW[(ko * 8 + no) * 64 + lane];
                acc[no] = __builtin_amdgcn_mfma_f32_16x16x32_bf16(a.s, b.s, acc[no], 0, 0, 0);
            }
        }
        #pragma unroll
        for (int no = 0; no < 8; ++no) {
            #pragma unroll
            for (int r = 0; r < 4; ++r) {
                float v = acc[no][r] + bcol[no];
                int grow = strip * 16 + kg * 4 + r;
                hout[(size_t)grow * HID + no * 16 + c] = v;
                ssum[no] += v;
                ssq[no] += v * v;
            }
        }
    }
    // column sums: lanes {c, c+16, c+32, c+48} hold disjoint row-groups -> reduce
    #pragma unroll
    for (int no = 0; no < 8; ++no) {
        ssum[no] += __shfl_xor(ssum[no], 16, 64);
        ssum[no] += __shfl_xor(ssum[no], 32, 64);
        ssq[no]  += __shfl_xor(ssq[no], 16, 64);
        ssq[no]  += __shfl_xor(ssq[no], 32, 64);
    }
    if (lane < 16) {
        #pragma unroll
        for (int no = 0; no < 8; ++no) {
            redS[wid][no * 16 + lane] = ssum[no];
            redQ[wid][no * 16 + lane] = ssq[no];
        }
    }
    __syncthreads();
    if (threadIdx.x < 128) {
        float ts = redS[0][threadIdx.x] + redS[1][threadIdx.x] + redS[2][threadIdx.x] + redS[3][threadIdx.x];
        float tq = redQ[0][threadIdx.x] + redQ[1][threadIdx.x] + redQ[2][threadIdx.x] + redQ[3][threadIdx.x];
        atomicAdd(&stats[threadIdx.x], ts);
        atomicAdd(&stats[HID + threadIdx.x], tq);
    }
}

__global__ void bnparam_kernel(const float* __restrict__ stats, const float* __restrict__ g,
                               const float* __restrict__ be, float* __restrict__ params, float invn) {
    int j = threadIdx.x;  // 128
    float mu = stats[j] * invn;
    float var = stats[HID + j] * invn - mu * mu;
    float a = g[j] * rsqrtf(var + 1e-5f);
    params[j] = a;
    params[HID + j] = be[j] - mu * a;
}

// read hin, normalize+relu; write fp32 (if hf32) and/or bf16 (if hbf)
__global__ void norm_relu_kernel(const float* __restrict__ hin, float* __restrict__ hf32,
                                 uint32_t* __restrict__ hbf, const float* __restrict__ params,
                                 int total) {
    int i = blockIdx.x * blockDim.x + threadIdx.x;
    if (i >= total) return;
    int cp = i & 63;
    float a0 = params[2 * cp], a1 = params[2 * cp + 1];
    float b0 = params[HID + 2 * cp], b1 = params[HID + 2 * cp + 1];
    float2 v = ((const float2*)hin)[i];
    v.x = fmaxf(fmaf(v.x, a0, b0), 0.f);
    v.y = fmaxf(fmaf(v.y, a1, b1), 0.f);
    if (hf32) ((float2*)hf32)[i] = v;
    if (hbf) hbf[i] = pack_bf16(v.x, v.y);
}

// per-row: out = relu(hn @ Wc1 + bc1) @ Wc2 + bc2 ; one wave per row, Wc1 in LDS
__global__ __launch_bounds__(256) void classifier_kernel(
    const float* __restrict__ hn, const float* __restrict__ Wc1, const float* __restrict__ bc1,
    const float* __restrict__ Wc2, const float* __restrict__ bc2, float* __restrict__ out, int n) {
    __shared__ float sW[HID * 64];
    __shared__ float sW2[64];
    for (int i = threadIdx.x; i < HID * 64 / 4; i += 256) ((float4*)sW)[i] = ((const float4*)Wc1)[i];
    if (threadIdx.x < 64) sW2[threadIdx.x] = Wc2[threadIdx.x];
    __syncthreads();
    int lane = threadIdx.x & 63;
    float b1v = bc1[lane];
    float b2v = bc2[0];
    int nwaves = (gridDim.x * blockDim.x) >> 6;
    int gw = (blockIdx.x * blockDim.x + threadIdx.x) >> 6;
    for (int row = gw; row < n; row += nwaves) {
        float2 hv = ((const float2*)hn)[(size_t)row * 64 + lane];
        float acc = b1v;
        #pragma unroll
        for (int k2 = 0; k2 < 64; ++k2) {
            float hx = __shfl(hv.x, k2, 64);
            float hy = __shfl(hv.y, k2, 64);
            acc = fmaf(hx, sW[(2 * k2) * 64 + lane], acc);
            acc = fmaf(hy, sW[(2 * k2 + 1) * 64 + lane], acc);
        }
        float p = fmaxf(acc, 0.f) * sW2[lane];
        #pragma unroll
        for (int o = 32; o >= 1; o >>= 1) p += __shfl_xor(p, o, 64);
        if (lane == 0) out[row] = p + b2v;
    }
}

extern "C" void kernel_launch(void* const* d_in, const int* in_sizes, int n_in,
                              void* d_out, int out_size, void* d_ws, size_t ws_size,
                              hipStream_t stream) {
    const float* x   = (const float*)d_in[0];
    const int*   ei  = (const int*)d_in[1];
    const float* Wn0 = (const float*)d_in[2];
    const float* b0  = (const float*)d_in[3];
    const float* Wr0 = (const float*)d_in[4];
    const float* g0  = (const float*)d_in[5];
    const float* be0 = (const float*)d_in[6];
    const float* Wn1 = (const float*)d_in[7];
    const float* b1  = (const float*)d_in[8];
    const float* Wr1 = (const float*)d_in[9];
    const float* g1  = (const float*)d_in[10];
    const float* be1 = (const float*)d_in[11];
    const float* Wc1 = (const float*)d_in[12];
    const float* bc1 = (const float*)d_in[13];
    const float* Wc2 = (const float*)d_in[14];
    const float* bc2 = (const float*)d_in[15];
    float* out = (float*)d_out;

    const int N = in_sizes[0] / HID;
    const int E = in_sizes[1] / 2;
    const int* srcv = ei;
    const int* tgtv = ei + E;

    size_t o = 0;
    auto carve = [&](size_t bytes) {
        void* p = (char*)d_ws + o;
        o += (bytes + 255) & ~(size_t)255;
        return p;
    };
    int* deg       = (int*)carve((size_t)N * 4);
    int* off       = (int*)carve((size_t)(N + 1) * 4);
    int* csr       = (int*)carve((size_t)E * 4);
    float* bufA    = (float*)carve((size_t)N * HID * 4);   // mean0 (bf16 alias) then h1 fp32
    float* bufB    = (float*)carve((size_t)N * HID * 4);   // h0 fp32 then mean1 (bf16 alias)
    uint32_t* fbf  = (uint32_t*)carve((size_t)N * HID * 2);  // bf16 gather features (x, then h0)
    uint32_t* Wp0  = (uint32_t*)carve(4096 * 16);
    uint32_t* Wp1  = (uint32_t*)carve(4096 * 16);
    int* partials  = (int*)carve(1024 * 4);
    float* stats0  = (float*)carve(256 * 4);
    float* stats1  = (float*)carve(256 * 4);
    float* params0 = (float*)carve(256 * 4);
    float* params1 = (float*)carve(256 * 4);
    (void)ws_size; (void)n_in; (void)out_size;

    uint32_t* mean0 = (uint32_t*)bufA;  // layer0 mean (bf16), dead once sage1 writes bufA
    uint32_t* mean1 = (uint32_t*)bufB;  // layer1 mean (bf16), overwrites dead h0 fp32

    hipMemsetAsync(deg, 0, (size_t)N * 4, stream);
    hipMemsetAsync(stats0, 0, 256 * 4, stream);
    hipMemsetAsync(stats1, 0, 256 * 4, stream);

    int eblocks = (E + 255) / 256;
    int nparts = (N + 1023) / 1024;

    hist_kernel<<<eblocks, 256, 0, stream>>>(tgtv, deg, E);
    partial_sum_kernel<<<nparts, 256, 0, stream>>>(deg, partials, N);
    scan_partials_kernel<<<1, 64, 0, stream>>>(partials, nparts);
    scan_final_kernel<<<nparts, 256, 0, stream>>>(deg, partials, off, N, E);
    hipMemsetAsync(deg, 0, (size_t)N * 4, stream);
    fill_kernel<<<eblocks, 256, 0, stream>>>(srcv, tgtv, off, deg, csr, E);

    pack_w_kernel<<<16, 256, 0, stream>>>(Wn0, Wr0, Wp0);
    pack_w_kernel<<<16, 256, 0, stream>>>(Wn1, Wr1, Wp1);

    int aggblocks = (N * 64 + 255) / 256;
    float invn = 1.0f / (float)N;

    // layer 0
    f32_to_bf16_kernel<<<aggblocks, 256, 0, stream>>>(x, fbf, N * 64);
    aggregate_bf16_kernel<<<aggblocks, 256, 0, stream>>>(fbf, off, csr, mean0, N);
    sage_mfma_kernel<<<256, 256, 0, stream>>>(mean0, fbf, Wp0, b0, bufB, stats0, N);
    bnparam_kernel<<<1, 128, 0, stream>>>(stats0, g0, be0, params0, invn);
    norm_relu_kernel<<<aggblocks, 256, 0, stream>>>(bufB, nullptr, fbf, params0, N * 64);

    // layer 1
    aggregate_bf16_kernel<<<aggblocks, 256, 0, stream>>>(fbf, off, csr, mean1, N);
    sage_mfma_kernel<<<256, 256, 0, stream>>>(mean1, fbf, Wp1, b1, bufA, stats1, N);
    bnparam_kernel<<<1, 128, 0, stream>>>(stats1, g1, be1, params1, invn);
    norm_relu_kernel<<<aggblocks, 256, 0, stream>>>(bufA, bufA, nullptr, params1, N * 64);

    // classifier
    classifier_kernel<<<1024, 256, 0, stream>>>(bufA, Wc1, bc1, Wc2, bc2, out, N);
}

// Round 6
// 758.519 us; speedup vs baseline: 2.1193x; 1.0843x over previous
//
#include <hip/hip_runtime.h>
#include <hip/hip_bf16.h>

// GraphSAGE 2-layer + BN + ReLU + MLP classifier.
// R6: XCD-partitioned CSR fill — each block only scatters targets in its
//     (blockIdx%8) node range, so csr/cnt lines stay in ONE per-XCD L2
//     (kills the 197MB write-amplification). Edge list re-read 8x (streaming).

#define HID 128

typedef __attribute__((ext_vector_type(8))) short short8;
typedef __attribute__((ext_vector_type(4))) float f32x4;

union FragU { uint4 u; short8 s; };

__device__ inline uint32_t pack_bf16(float a, float b) {
    uint32_t ua = __float_as_uint(a);
    uint32_t ub = __float_as_uint(b);
    ua = ua + 0x7fffu + ((ua >> 16) & 1u);  // RNE
    ub = ub + 0x7fffu + ((ub >> 16) & 1u);
    return (ua >> 16) | (ub & 0xffff0000u);
}

__global__ void hist_kernel(const int* __restrict__ tgt, int* __restrict__ deg, int e) {
    int i = blockIdx.x * blockDim.x + threadIdx.x;
    if (i < e) atomicAdd(&deg[tgt[i]], 1);
}

// ---- parallel scan: partials -> scan partials -> final ----
__global__ void partial_sum_kernel(const int* __restrict__ deg, int* __restrict__ partials, int n) {
    __shared__ int ws[4];
    int base = blockIdx.x * 1024;
    int tid = threadIdx.x;
    int i = base + tid * 4;
    int s = 0;
    if (i + 3 < n) {
        int4 v = *(const int4*)(deg + i);
        s = v.x + v.y + v.z + v.w;
    } else {
        for (int k = 0; k < 4; ++k) if (i + k < n) s += deg[i + k];
    }
    #pragma unroll
    for (int o = 1; o < 64; o <<= 1) s += __shfl_xor(s, o, 64);
    if ((tid & 63) == 0) ws[tid >> 6] = s;
    __syncthreads();
    if (tid == 0) partials[blockIdx.x] = ws[0] + ws[1] + ws[2] + ws[3];
}

__global__ void scan_partials_kernel(int* __restrict__ partials, int np) {
    int lane = threadIdx.x;  // 64 threads
    int carry = 0;
    for (int base = 0; base < np; base += 64) {
        int i = base + lane;
        int v = (i < np) ? partials[i] : 0;
        int s = v;
        #pragma unroll
        for (int o = 1; o < 64; o <<= 1) {
            int t = __shfl_up(s, o, 64);
            if (lane >= o) s += t;
        }
        if (i < np) partials[i] = carry + s - v;  // exclusive
        carry += __shfl(s, 63, 64);
    }
}

__global__ void scan_final_kernel(const int* __restrict__ deg, const int* __restrict__ partials,
                                  int* __restrict__ off, int n, int e) {
    __shared__ int wsum[4];
    __shared__ int wpre[4];
    int base = blockIdx.x * 1024;
    int tid = threadIdx.x;
    int lane = tid & 63, wid = tid >> 6;
    int i = base + tid * 4;
    int v[4];
    #pragma unroll
    for (int k = 0; k < 4; ++k) v[k] = (i + k < n) ? deg[i + k] : 0;
    int tsum = v[0] + v[1] + v[2] + v[3];
    int s = tsum;
    #pragma unroll
    for (int o = 1; o < 64; o <<= 1) {
        int t = __shfl_up(s, o, 64);
        if (lane >= o) s += t;
    }
    if (lane == 63) wsum[wid] = s;
    __syncthreads();
    if (tid == 0) {
        int c = 0;
        #pragma unroll
        for (int w = 0; w < 4; ++w) { wpre[w] = c; c += wsum[w]; }
    }
    __syncthreads();
    int excl = partials[blockIdx.x] + wpre[wid] + (s - tsum);
    #pragma unroll
    for (int k = 0; k < 4; ++k) {
        if (i + k < n) off[i + k] = excl;
        excl += v[k];
    }
    if (blockIdx.x == 0 && tid == 0) off[n] = e;
}

// XCD-partitioned fill: block handles only targets in [(blockIdx&7)*npb, +npb).
// Blocks round-robin to XCDs, so each XCD's L2 owns a 1.6MB csr slice that
// collects all its writes before writeback. Edge list streamed 8x (int4).
__global__ __launch_bounds__(256) void fill_kernel(
    const int* __restrict__ src, const int* __restrict__ tgt,
    const int* __restrict__ off, int* __restrict__ cnt,
    int* __restrict__ csr, int e, int npb) {
    int r = blockIdx.x & 7;
    int lo = r * npb, hi = lo + npb;
    int g = (blockIdx.x >> 3) * blockDim.x + threadIdx.x;
    int gs = (gridDim.x >> 3) * blockDim.x;
    int ngroups = e >> 2;  // E % 4 == 0 (3.2M)
    for (int i = g; i < ngroups; i += gs) {
        int4 t4 = ((const int4*)tgt)[i];
        int4 s4 = ((const int4*)src)[i];
        #pragma unroll
        for (int k = 0; k < 4; ++k) {
            int t = (&t4.x)[k];
            if (t >= lo && t < hi) {
                int slot = off[t] + atomicAdd(&cnt[t], 1);
                csr[slot] = (&s4.x)[k];
            }
        }
    }
}

__global__ void f32_to_bf16_kernel(const float* __restrict__ in, uint32_t* __restrict__ out, int n2) {
    int i = blockIdx.x * blockDim.x + threadIdx.x;
    if (i < n2) {
        float2 v = ((const float2*)in)[i];
        out[i] = pack_bf16(v.x, v.y);
    }
}

// Pack [Wn;Wr] (two 128x128 row-major f32, W[k][n]) into MFMA B-frag bf16 layout:
// packed16B[(ko*8+no)*64 + lane] = 8 bf16: W[ko*32+(lane>>4)*8+j][no*16+(lane&15)]
__global__ void pack_w_kernel(const float* __restrict__ Wn, const float* __restrict__ Wr,
                              uint32_t* __restrict__ packed) {
    int t = blockIdx.x * blockDim.x + threadIdx.x;  // 4096 threads
    if (t >= 4096) return;
    int lane = t & 63;
    int no = (t >> 6) & 7;
    int ko = t >> 9;
    int n = no * 16 + (lane & 15);
    int kbase = ko * 32 + ((lane >> 4) << 3);
    uint32_t v[4];
    #pragma unroll
    for (int jj = 0; jj < 4; ++jj) {
        int k0 = kbase + jj * 2, k1 = k0 + 1;
        float a = (k0 < 128) ? Wn[k0 * 128 + n] : Wr[(k0 - 128) * 128 + n];
        float b = (k1 < 128) ? Wn[k1 * 128 + n] : Wr[(k1 - 128) * 128 + n];
        v[jj] = pack_bf16(a, b);
    }
    uint4 u4; u4.x = v[0]; u4.y = v[1]; u4.z = v[2]; u4.w = v[3];
    ((uint4*)packed)[t] = u4;
}

// one wave per node; 4 edges/iter, dwordx4, wave-uniform __shfl broadcast.
// Output: bf16 mean row (64 uint32 per node).
__global__ __launch_bounds__(256) void aggregate_bf16_kernel(
    const uint32_t* __restrict__ feat, const int* __restrict__ off,
    const int* __restrict__ csr, uint32_t* __restrict__ outmean, int n) {
    int wv = (blockIdx.x * blockDim.x + threadIdx.x) >> 6;
    int lane = threadIdx.x & 63;
    if (wv >= n) return;
    int beg = off[wv], end = off[wv + 1];
    int len = end - beg;
    int sub = lane >> 4;
    int c   = lane & 15;
    float acc[8];
    #pragma unroll
    for (int k = 0; k < 8; ++k) acc[k] = 0.f;
    for (int base = 0; base < len; base += 64) {
        int m = len - base; if (m > 64) m = 64;
        int idx = csr[beg + base + (lane < m ? lane : 0)];
        for (int j0 = 0; j0 < m; j0 += 4) {           // wave-uniform trip count
            int j = j0 + sub;
            int s = __shfl(idx, (j < m ? j : 0), 64); // all lanes active
            if (j < m) {
                uint4 u = *(const uint4*)(feat + (size_t)s * 64 + c * 4);
                acc[0] += __uint_as_float(u.x << 16);
                acc[1] += __uint_as_float(u.x & 0xffff0000u);
                acc[2] += __uint_as_float(u.y << 16);
                acc[3] += __uint_as_float(u.y & 0xffff0000u);
                acc[4] += __uint_as_float(u.z << 16);
                acc[5] += __uint_as_float(u.z & 0xffff0000u);
                acc[6] += __uint_as_float(u.w << 16);
                acc[7] += __uint_as_float(u.w & 0xffff0000u);
            }
        }
    }
    #pragma unroll
    for (int k = 0; k < 8; ++k) {
        acc[k] += __shfl_xor(acc[k], 16, 64);
        acc[k] += __shfl_xor(acc[k], 32, 64);
    }
    float inv = 1.0f / fmaxf((float)len, 1.0f);
    outmean[(size_t)wv * 64 + c * 4 + sub] = pack_bf16(acc[sub * 2] * inv, acc[sub * 2 + 1] * inv);
}

// h = [mean|x](bf16) @ Wpacked(256x128 bf16) + b via 16x16x32 bf16 MFMA.
// Each wave: one 16-row strip, full 128 cols (8 n-tiles), K=256 (8 k-tiles).
// Also accumulates per-column sum/sumsq -> stats (atomics per block).
__global__ __launch_bounds__(256) void sage_mfma_kernel(
    const uint32_t* __restrict__ meanbf, const uint32_t* __restrict__ xbf,
    const uint32_t* __restrict__ Wp, const float* __restrict__ bias,
    float* __restrict__ hout, float* __restrict__ stats, int n) {
    __shared__ uint4 sW[4096];          // 64 KB packed weights
    __shared__ float redS[4][128];
    __shared__ float redQ[4][128];
    for (int i = threadIdx.x; i < 4096; i += 256) sW[i] = ((const uint4*)Wp)[i];
    __syncthreads();
    int lane = threadIdx.x & 63;
    int wid = threadIdx.x >> 6;
    int c = lane & 15;     // A row within strip / C col within n-tile
    int kg = lane >> 4;    // k-group / C row-group
    float bcol[8];
    #pragma unroll
    for (int no = 0; no < 8; ++no) bcol[no] = bias[no * 16 + c];
    float ssum[8], ssq[8];
    #pragma unroll
    for (int no = 0; no < 8; ++no) { ssum[no] = 0.f; ssq[no] = 0.f; }
    int nstrips = n >> 4;  // n % 16 == 0 (N=100000)
    int sstride = gridDim.x * 4;
    for (int strip = blockIdx.x * 4 + wid; strip < nstrips; strip += sstride) {
        const uint4* mrow = (const uint4*)(meanbf + (size_t)(strip * 16 + c) * 64);
        const uint4* xrow = (const uint4*)(xbf + (size_t)(strip * 16 + c) * 64);
        f32x4 acc[8];
        #pragma unroll
        for (int no = 0; no < 8; ++no) acc[no] = (f32x4){0.f, 0.f, 0.f, 0.f};
        #pragma unroll
        for (int ko = 0; ko < 8; ++ko) {
            FragU a;
            a.u = (ko < 4) ? mrow[ko * 4 + kg] : xrow[(ko - 4) * 4 + kg];
            #pragma unroll
            for (int no = 0; no < 8; ++no) {
                FragU b;
                b.u = sW[(ko * 8 + no) * 64 + lane];
                acc[no] = __builtin_amdgcn_mfma_f32_16x16x32_bf16(a.s, b.s, acc[no], 0, 0, 0);
            }
        }
        #pragma unroll
        for (int no = 0; no < 8; ++no) {
            #pragma unroll
            for (int r = 0; r < 4; ++r) {
                float v = acc[no][r] + bcol[no];
                int grow = strip * 16 + kg * 4 + r;
                hout[(size_t)grow * HID + no * 16 + c] = v;
                ssum[no] += v;
                ssq[no] += v * v;
            }
        }
    }
    // column sums: lanes {c, c+16, c+32, c+48} hold disjoint row-groups -> reduce
    #pragma unroll
    for (int no = 0; no < 8; ++no) {
        ssum[no] += __shfl_xor(ssum[no], 16, 64);
        ssum[no] += __shfl_xor(ssum[no], 32, 64);
        ssq[no]  += __shfl_xor(ssq[no], 16, 64);
        ssq[no]  += __shfl_xor(ssq[no], 32, 64);
    }
    if (lane < 16) {
        #pragma unroll
        for (int no = 0; no < 8; ++no) {
            redS[wid][no * 16 + lane] = ssum[no];
            redQ[wid][no * 16 + lane] = ssq[no];
        }
    }
    __syncthreads();
    if (threadIdx.x < 128) {
        float ts = redS[0][threadIdx.x] + redS[1][threadIdx.x] + redS[2][threadIdx.x] + redS[3][threadIdx.x];
        float tq = redQ[0][threadIdx.x] + redQ[1][threadIdx.x] + redQ[2][threadIdx.x] + redQ[3][threadIdx.x];
        atomicAdd(&stats[threadIdx.x], ts);
        atomicAdd(&stats[HID + threadIdx.x], tq);
    }
}

__global__ void bnparam_kernel(const float* __restrict__ stats, const float* __restrict__ g,
                               const float* __restrict__ be, float* __restrict__ params, float invn) {
    int j = threadIdx.x;  // 128
    float mu = stats[j] * invn;
    float var = stats[HID + j] * invn - mu * mu;
    float a = g[j] * rsqrtf(var + 1e-5f);
    params[j] = a;
    params[HID + j] = be[j] - mu * a;
}

// read hin, normalize+relu; write fp32 (if hf32) and/or bf16 (if hbf)
__global__ void norm_relu_kernel(const float* __restrict__ hin, float* __restrict__ hf32,
                                 uint32_t* __restrict__ hbf, const float* __restrict__ params,
                                 int total) {
    int i = blockIdx.x * blockDim.x + threadIdx.x;
    if (i >= total) return;
    int cp = i & 63;
    float a0 = params[2 * cp], a1 = params[2 * cp + 1];
    float b0 = params[HID + 2 * cp], b1 = params[HID + 2 * cp + 1];
    float2 v = ((const float2*)hin)[i];
    v.x = fmaxf(fmaf(v.x, a0, b0), 0.f);
    v.y = fmaxf(fmaf(v.y, a1, b1), 0.f);
    if (hf32) ((float2*)hf32)[i] = v;
    if (hbf) hbf[i] = pack_bf16(v.x, v.y);
}

// per-row: out = relu(hn @ Wc1 + bc1) @ Wc2 + bc2 ; one wave per row, Wc1 in LDS
__global__ __launch_bounds__(256) void classifier_kernel(
    const float* __restrict__ hn, const float* __restrict__ Wc1, const float* __restrict__ bc1,
    const float* __restrict__ Wc2, const float* __restrict__ bc2, float* __restrict__ out, int n) {
    __shared__ float sW[HID * 64];
    __shared__ float sW2[64];
    for (int i = threadIdx.x; i < HID * 64 / 4; i += 256) ((float4*)sW)[i] = ((const float4*)Wc1)[i];
    if (threadIdx.x < 64) sW2[threadIdx.x] = Wc2[threadIdx.x];
    __syncthreads();
    int lane = threadIdx.x & 63;
    float b1v = bc1[lane];
    float b2v = bc2[0];
    int nwaves = (gridDim.x * blockDim.x) >> 6;
    int gw = (blockIdx.x * blockDim.x + threadIdx.x) >> 6;
    for (int row = gw; row < n; row += nwaves) {
        float2 hv = ((const float2*)hn)[(size_t)row * 64 + lane];
        float acc = b1v;
        #pragma unroll
        for (int k2 = 0; k2 < 64; ++k2) {
            float hx = __shfl(hv.x, k2, 64);
            float hy = __shfl(hv.y, k2, 64);
            acc = fmaf(hx, sW[(2 * k2) * 64 + lane], acc);
            acc = fmaf(hy, sW[(2 * k2 + 1) * 64 + lane], acc);
        }
        float p = fmaxf(acc, 0.f) * sW2[lane];
        #pragma unroll
        for (int o = 32; o >= 1; o >>= 1) p += __shfl_xor(p, o, 64);
        if (lane == 0) out[row] = p + b2v;
    }
}

extern "C" void kernel_launch(void* const* d_in, const int* in_sizes, int n_in,
                              void* d_out, int out_size, void* d_ws, size_t ws_size,
                              hipStream_t stream) {
    const float* x   = (const float*)d_in[0];
    const int*   ei  = (const int*)d_in[1];
    const float* Wn0 = (const float*)d_in[2];
    const float* b0  = (const float*)d_in[3];
    const float* Wr0 = (const float*)d_in[4];
    const float* g0  = (const float*)d_in[5];
    const float* be0 = (const float*)d_in[6];
    const float* Wn1 = (const float*)d_in[7];
    const float* b1  = (const float*)d_in[8];
    const float* Wr1 = (const float*)d_in[9];
    const float* g1  = (const float*)d_in[10];
    const float* be1 = (const float*)d_in[11];
    const float* Wc1 = (const float*)d_in[12];
    const float* bc1 = (const float*)d_in[13];
    const float* Wc2 = (const float*)d_in[14];
    const float* bc2 = (const float*)d_in[15];
    float* out = (float*)d_out;

    const int N = in_sizes[0] / HID;
    const int E = in_sizes[1] / 2;
    const int* srcv = ei;
    const int* tgtv = ei + E;

    size_t o = 0;
    auto carve = [&](size_t bytes) {
        void* p = (char*)d_ws + o;
        o += (bytes + 255) & ~(size_t)255;
        return p;
    };
    int* deg       = (int*)carve((size_t)N * 4);
    int* off       = (int*)carve((size_t)(N + 1) * 4);
    int* csr       = (int*)carve((size_t)E * 4);
    float* bufA    = (float*)carve((size_t)N * HID * 4);   // mean0 (bf16 alias) then h1 fp32
    float* bufB    = (float*)carve((size_t)N * HID * 4);   // h0 fp32 then mean1 (bf16 alias)
    uint32_t* fbf  = (uint32_t*)carve((size_t)N * HID * 2);  // bf16 gather features (x, then h0)
    uint32_t* Wp0  = (uint32_t*)carve(4096 * 16);
    uint32_t* Wp1  = (uint32_t*)carve(4096 * 16);
    int* partials  = (int*)carve(1024 * 4);
    float* stats0  = (float*)carve(256 * 4);
    float* stats1  = (float*)carve(256 * 4);
    float* params0 = (float*)carve(256 * 4);
    float* params1 = (float*)carve(256 * 4);
    (void)ws_size; (void)n_in; (void)out_size;

    uint32_t* mean0 = (uint32_t*)bufA;  // layer0 mean (bf16), dead once sage1 writes bufA
    uint32_t* mean1 = (uint32_t*)bufB;  // layer1 mean (bf16), overwrites dead h0 fp32

    hipMemsetAsync(deg, 0, (size_t)N * 4, stream);
    hipMemsetAsync(stats0, 0, 256 * 4, stream);
    hipMemsetAsync(stats1, 0, 256 * 4, stream);

    int eblocks = (E + 255) / 256;
    int nparts = (N + 1023) / 1024;
    int npb = (N + 7) / 8;  // nodes per XCD bucket

    hist_kernel<<<eblocks, 256, 0, stream>>>(tgtv, deg, E);
    partial_sum_kernel<<<nparts, 256, 0, stream>>>(deg, partials, N);
    scan_partials_kernel<<<1, 64, 0, stream>>>(partials, nparts);
    scan_final_kernel<<<nparts, 256, 0, stream>>>(deg, partials, off, N, E);
    hipMemsetAsync(deg, 0, (size_t)N * 4, stream);
    fill_kernel<<<2048, 256, 0, stream>>>(srcv, tgtv, off, deg, csr, E, npb);

    pack_w_kernel<<<16, 256, 0, stream>>>(Wn0, Wr0, Wp0);
    pack_w_kernel<<<16, 256, 0, stream>>>(Wn1, Wr1, Wp1);

    int aggblocks = (N * 64 + 255) / 256;
    float invn = 1.0f / (float)N;

    // layer 0
    f32_to_bf16_kernel<<<aggblocks, 256, 0, stream>>>(x, fbf, N * 64);
    aggregate_bf16_kernel<<<aggblocks, 256, 0, stream>>>(fbf, off, csr, mean0, N);
    sage_mfma_kernel<<<256, 256, 0, stream>>>(mean0, fbf, Wp0, b0, bufB, stats0, N);
    bnparam_kernel<<<1, 128, 0, stream>>>(stats0, g0, be0, params0, invn);
    norm_relu_kernel<<<aggblocks, 256, 0, stream>>>(bufB, nullptr, fbf, params0, N * 64);

    // layer 1
    aggregate_bf16_kernel<<<aggblocks, 256, 0, stream>>>(fbf, off, csr, mean1, N);
    sage_mfma_kernel<<<256, 256, 0, stream>>>(mean1, fbf, Wp1, b1, bufA, stats1, N);
    bnparam_kernel<<<1, 128, 0, stream>>>(stats1, g1, be1, params1, invn);
    norm_relu_kernel<<<aggblocks, 256, 0, stream>>>(bufA, bufA, nullptr, params1, N * 64);

    // classifier
    classifier_kernel<<<1024, 256, 0, stream>>>(bufA, Wc1, bc1, Wc2, bc2, out, N);
}

// Round 7
// 620.462 us; speedup vs baseline: 2.5909x; 1.2225x over previous
//
#include <hip/hip_runtime.h>
#include <hip/hip_bf16.h>

// GraphSAGE 2-layer + BN + ReLU + MLP classifier.
// R7: classifier -> MFMA bf16 (16-row strips, Wc2 folded into epilogue,
//     cross-lane column reduce). norm_relu1 emits bf16 only (no fp32 h1).

#define HID 128

typedef __attribute__((ext_vector_type(8))) short short8;
typedef __attribute__((ext_vector_type(4))) float f32x4;

union FragU { uint4 u; short8 s; };

__device__ inline uint32_t pack_bf16(float a, float b) {
    uint32_t ua = __float_as_uint(a);
    uint32_t ub = __float_as_uint(b);
    ua = ua + 0x7fffu + ((ua >> 16) & 1u);  // RNE
    ub = ub + 0x7fffu + ((ub >> 16) & 1u);
    return (ua >> 16) | (ub & 0xffff0000u);
}

__global__ void hist_kernel(const int* __restrict__ tgt, int* __restrict__ deg, int e) {
    int i = blockIdx.x * blockDim.x + threadIdx.x;
    if (i < e) atomicAdd(&deg[tgt[i]], 1);
}

// ---- parallel scan: partials -> scan partials -> final ----
__global__ void partial_sum_kernel(const int* __restrict__ deg, int* __restrict__ partials, int n) {
    __shared__ int ws[4];
    int base = blockIdx.x * 1024;
    int tid = threadIdx.x;
    int i = base + tid * 4;
    int s = 0;
    if (i + 3 < n) {
        int4 v = *(const int4*)(deg + i);
        s = v.x + v.y + v.z + v.w;
    } else {
        for (int k = 0; k < 4; ++k) if (i + k < n) s += deg[i + k];
    }
    #pragma unroll
    for (int o = 1; o < 64; o <<= 1) s += __shfl_xor(s, o, 64);
    if ((tid & 63) == 0) ws[tid >> 6] = s;
    __syncthreads();
    if (tid == 0) partials[blockIdx.x] = ws[0] + ws[1] + ws[2] + ws[3];
}

__global__ void scan_partials_kernel(int* __restrict__ partials, int np) {
    int lane = threadIdx.x;  // 64 threads
    int carry = 0;
    for (int base = 0; base < np; base += 64) {
        int i = base + lane;
        int v = (i < np) ? partials[i] : 0;
        int s = v;
        #pragma unroll
        for (int o = 1; o < 64; o <<= 1) {
            int t = __shfl_up(s, o, 64);
            if (lane >= o) s += t;
        }
        if (i < np) partials[i] = carry + s - v;  // exclusive
        carry += __shfl(s, 63, 64);
    }
}

__global__ void scan_final_kernel(const int* __restrict__ deg, const int* __restrict__ partials,
                                  int* __restrict__ off, int n, int e) {
    __shared__ int wsum[4];
    __shared__ int wpre[4];
    int base = blockIdx.x * 1024;
    int tid = threadIdx.x;
    int lane = tid & 63, wid = tid >> 6;
    int i = base + tid * 4;
    int v[4];
    #pragma unroll
    for (int k = 0; k < 4; ++k) v[k] = (i + k < n) ? deg[i + k] : 0;
    int tsum = v[0] + v[1] + v[2] + v[3];
    int s = tsum;
    #pragma unroll
    for (int o = 1; o < 64; o <<= 1) {
        int t = __shfl_up(s, o, 64);
        if (lane >= o) s += t;
    }
    if (lane == 63) wsum[wid] = s;
    __syncthreads();
    if (tid == 0) {
        int c = 0;
        #pragma unroll
        for (int w = 0; w < 4; ++w) { wpre[w] = c; c += wsum[w]; }
    }
    __syncthreads();
    int excl = partials[blockIdx.x] + wpre[wid] + (s - tsum);
    #pragma unroll
    for (int k = 0; k < 4; ++k) {
        if (i + k < n) off[i + k] = excl;
        excl += v[k];
    }
    if (blockIdx.x == 0 && tid == 0) off[n] = e;
}

// XCD-partitioned fill: block handles only targets in [(blockIdx&7)*npb, +npb).
__global__ __launch_bounds__(256) void fill_kernel(
    const int* __restrict__ src, const int* __restrict__ tgt,
    const int* __restrict__ off, int* __restrict__ cnt,
    int* __restrict__ csr, int e, int npb) {
    int r = blockIdx.x & 7;
    int lo = r * npb, hi = lo + npb;
    int g = (blockIdx.x >> 3) * blockDim.x + threadIdx.x;
    int gs = (gridDim.x >> 3) * blockDim.x;
    int ngroups = e >> 2;  // E % 4 == 0 (3.2M)
    for (int i = g; i < ngroups; i += gs) {
        int4 t4 = ((const int4*)tgt)[i];
        int4 s4 = ((const int4*)src)[i];
        #pragma unroll
        for (int k = 0; k < 4; ++k) {
            int t = (&t4.x)[k];
            if (t >= lo && t < hi) {
                int slot = off[t] + atomicAdd(&cnt[t], 1);
                csr[slot] = (&s4.x)[k];
            }
        }
    }
}

__global__ void f32_to_bf16_kernel(const float* __restrict__ in, uint32_t* __restrict__ out, int n2) {
    int i = blockIdx.x * blockDim.x + threadIdx.x;
    if (i < n2) {
        float2 v = ((const float2*)in)[i];
        out[i] = pack_bf16(v.x, v.y);
    }
}

// Pack [Wn;Wr] (two 128x128 row-major f32, W[k][n]) into MFMA B-frag bf16 layout:
// packed16B[(ko*8+no)*64 + lane] = 8 bf16: W[ko*32+(lane>>4)*8+j][no*16+(lane&15)]
__global__ void pack_w_kernel(const float* __restrict__ Wn, const float* __restrict__ Wr,
                              uint32_t* __restrict__ packed) {
    int t = blockIdx.x * blockDim.x + threadIdx.x;  // 4096 threads
    if (t >= 4096) return;
    int lane = t & 63;
    int no = (t >> 6) & 7;
    int ko = t >> 9;
    int n = no * 16 + (lane & 15);
    int kbase = ko * 32 + ((lane >> 4) << 3);
    uint32_t v[4];
    #pragma unroll
    for (int jj = 0; jj < 4; ++jj) {
        int k0 = kbase + jj * 2, k1 = k0 + 1;
        float a = (k0 < 128) ? Wn[k0 * 128 + n] : Wr[(k0 - 128) * 128 + n];
        float b = (k1 < 128) ? Wn[k1 * 128 + n] : Wr[(k1 - 128) * 128 + n];
        v[jj] = pack_bf16(a, b);
    }
    uint4 u4; u4.x = v[0]; u4.y = v[1]; u4.z = v[2]; u4.w = v[3];
    ((uint4*)packed)[t] = u4;
}

// Pack Wc1 [128][64] f32 into B-frag layout: 4 ko x 4 no x 64 lanes x 16B = 16KB
__global__ void pack_wc_kernel(const float* __restrict__ Wc1, uint32_t* __restrict__ packed) {
    int t = blockIdx.x * blockDim.x + threadIdx.x;  // 1024 threads
    if (t >= 1024) return;
    int lane = t & 63;
    int no = (t >> 6) & 3;
    int ko = t >> 8;
    int n = no * 16 + (lane & 15);
    int kbase = ko * 32 + ((lane >> 4) << 3);
    uint32_t v[4];
    #pragma unroll
    for (int jj = 0; jj < 4; ++jj) {
        int k0 = kbase + jj * 2;
        v[jj] = pack_bf16(Wc1[k0 * 64 + n], Wc1[(k0 + 1) * 64 + n]);
    }
    uint4 u4; u4.x = v[0]; u4.y = v[1]; u4.z = v[2]; u4.w = v[3];
    ((uint4*)packed)[t] = u4;
}

// one wave per node; 4 edges/iter, dwordx4, wave-uniform __shfl broadcast.
__global__ __launch_bounds__(256) void aggregate_bf16_kernel(
    const uint32_t* __restrict__ feat, const int* __restrict__ off,
    const int* __restrict__ csr, uint32_t* __restrict__ outmean, int n) {
    int wv = (blockIdx.x * blockDim.x + threadIdx.x) >> 6;
    int lane = threadIdx.x & 63;
    if (wv >= n) return;
    int beg = off[wv], end = off[wv + 1];
    int len = end - beg;
    int sub = lane >> 4;
    int c   = lane & 15;
    float acc[8];
    #pragma unroll
    for (int k = 0; k < 8; ++k) acc[k] = 0.f;
    for (int base = 0; base < len; base += 64) {
        int m = len - base; if (m > 64) m = 64;
        int idx = csr[beg + base + (lane < m ? lane : 0)];
        for (int j0 = 0; j0 < m; j0 += 4) {           // wave-uniform trip count
            int j = j0 + sub;
            int s = __shfl(idx, (j < m ? j : 0), 64); // all lanes active
            if (j < m) {
                uint4 u = *(const uint4*)(feat + (size_t)s * 64 + c * 4);
                acc[0] += __uint_as_float(u.x << 16);
                acc[1] += __uint_as_float(u.x & 0xffff0000u);
                acc[2] += __uint_as_float(u.y << 16);
                acc[3] += __uint_as_float(u.y & 0xffff0000u);
                acc[4] += __uint_as_float(u.z << 16);
                acc[5] += __uint_as_float(u.z & 0xffff0000u);
                acc[6] += __uint_as_float(u.w << 16);
                acc[7] += __uint_as_float(u.w & 0xffff0000u);
            }
        }
    }
    #pragma unroll
    for (int k = 0; k < 8; ++k) {
        acc[k] += __shfl_xor(acc[k], 16, 64);
        acc[k] += __shfl_xor(acc[k], 32, 64);
    }
    float inv = 1.0f / fmaxf((float)len, 1.0f);
    outmean[(size_t)wv * 64 + c * 4 + sub] = pack_bf16(acc[sub * 2] * inv, acc[sub * 2 + 1] * inv);
}

// h = [mean|x](bf16) @ Wpacked(256x128 bf16) + b via 16x16x32 bf16 MFMA.
__global__ __launch_bounds__(256) void sage_mfma_kernel(
    const uint32_t* __restrict__ meanbf, const uint32_t* __restrict__ xbf,
    const uint32_t* __restrict__ Wp, const float* __restrict__ bias,
    float* __restrict__ hout, float* __restrict__ stats, int n) {
    __shared__ uint4 sW[4096];          // 64 KB packed weights
    __shared__ float redS[4][128];
    __shared__ float redQ[4][128];
    for (int i = threadIdx.x; i < 4096; i += 256) sW[i] = ((const uint4*)Wp)[i];
    __syncthreads();
    int lane = threadIdx.x & 63;
    int wid = threadIdx.x >> 6;
    int c = lane & 15;     // A row within strip / C col within n-tile
    int kg = lane >> 4;    // k-group / C row-group
    float bcol[8];
    #pragma unroll
    for (int no = 0; no < 8; ++no) bcol[no] = bias[no * 16 + c];
    float ssum[8], ssq[8];
    #pragma unroll
    for (int no = 0; no < 8; ++no) { ssum[no] = 0.f; ssq[no] = 0.f; }
    int nstrips = n >> 4;  // n % 16 == 0 (N=100000)
    int sstride = gridDim.x * 4;
    for (int strip = blockIdx.x * 4 + wid; strip < nstrips; strip += sstride) {
        const uint4* mrow = (const uint4*)(meanbf + (size_t)(strip * 16 + c) * 64);
        const uint4* xrow = (const uint4*)(xbf + (size_t)(strip * 16 + c) * 64);
        f32x4 acc[8];
        #pragma unroll
        for (int no = 0; no < 8; ++no) acc[no] = (f32x4){0.f, 0.f, 0.f, 0.f};
        #pragma unroll
        for (int ko = 0; ko < 8; ++ko) {
            FragU a;
            a.u = (ko < 4) ? mrow[ko * 4 + kg] : xrow[(ko - 4) * 4 + kg];
            #pragma unroll
            for (int no = 0; no < 8; ++no) {
                FragU b;
                b.u = sW[(ko * 8 + no) * 64 + lane];
                acc[no] = __builtin_amdgcn_mfma_f32_16x16x32_bf16(a.s, b.s, acc[no], 0, 0, 0);
            }
        }
        #pragma unroll
        for (int no = 0; no < 8; ++no) {
            #pragma unroll
            for (int r = 0; r < 4; ++r) {
                float v = acc[no][r] + bcol[no];
                int grow = strip * 16 + kg * 4 + r;
                hout[(size_t)grow * HID + no * 16 + c] = v;
                ssum[no] += v;
                ssq[no] += v * v;
            }
        }
    }
    #pragma unroll
    for (int no = 0; no < 8; ++no) {
        ssum[no] += __shfl_xor(ssum[no], 16, 64);
        ssum[no] += __shfl_xor(ssum[no], 32, 64);
        ssq[no]  += __shfl_xor(ssq[no], 16, 64);
        ssq[no]  += __shfl_xor(ssq[no], 32, 64);
    }
    if (lane < 16) {
        #pragma unroll
        for (int no = 0; no < 8; ++no) {
            redS[wid][no * 16 + lane] = ssum[no];
            redQ[wid][no * 16 + lane] = ssq[no];
        }
    }
    __syncthreads();
    if (threadIdx.x < 128) {
        float ts = redS[0][threadIdx.x] + redS[1][threadIdx.x] + redS[2][threadIdx.x] + redS[3][threadIdx.x];
        float tq = redQ[0][threadIdx.x] + redQ[1][threadIdx.x] + redQ[2][threadIdx.x] + redQ[3][threadIdx.x];
        atomicAdd(&stats[threadIdx.x], ts);
        atomicAdd(&stats[HID + threadIdx.x], tq);
    }
}

__global__ void bnparam_kernel(const float* __restrict__ stats, const float* __restrict__ g,
                               const float* __restrict__ be, float* __restrict__ params, float invn) {
    int j = threadIdx.x;  // 128
    float mu = stats[j] * invn;
    float var = stats[HID + j] * invn - mu * mu;
    float a = g[j] * rsqrtf(var + 1e-5f);
    params[j] = a;
    params[HID + j] = be[j] - mu * a;
}

// read hin, normalize+relu; write fp32 (if hf32) and/or bf16 (if hbf)
__global__ void norm_relu_kernel(const float* __restrict__ hin, float* __restrict__ hf32,
                                 uint32_t* __restrict__ hbf, const float* __restrict__ params,
                                 int total) {
    int i = blockIdx.x * blockDim.x + threadIdx.x;
    if (i >= total) return;
    int cp = i & 63;
    float a0 = params[2 * cp], a1 = params[2 * cp + 1];
    float b0 = params[HID + 2 * cp], b1 = params[HID + 2 * cp + 1];
    float2 v = ((const float2*)hin)[i];
    v.x = fmaxf(fmaf(v.x, a0, b0), 0.f);
    v.y = fmaxf(fmaf(v.y, a1, b1), 0.f);
    if (hf32) ((float2*)hf32)[i] = v;
    if (hbf) hbf[i] = pack_bf16(v.x, v.y);
}

// classifier via MFMA: out = relu(hn@Wc1+bc1)@Wc2 + bc2.
// Wave strip = 16 rows; K=128 (4 k-tiles), 4 n-tiles; Wc2 folded in epilogue.
__global__ __launch_bounds__(256) void classifier_mfma_kernel(
    const uint32_t* __restrict__ hnbf, const uint32_t* __restrict__ Wcp,
    const float* __restrict__ bc1, const float* __restrict__ Wc2,
    const float* __restrict__ bc2, float* __restrict__ out, int n) {
    __shared__ uint4 sW[1024];  // 16 KB packed Wc1
    for (int i = threadIdx.x; i < 1024; i += 256) sW[i] = ((const uint4*)Wcp)[i];
    __syncthreads();
    int lane = threadIdx.x & 63;
    int wid = threadIdx.x >> 6;
    int c = lane & 15;
    int kg = lane >> 4;
    float b1v[4], w2v[4];
    #pragma unroll
    for (int no = 0; no < 4; ++no) {
        b1v[no] = bc1[no * 16 + c];
        w2v[no] = Wc2[no * 16 + c];
    }
    float b2v = bc2[0];
    int nstrips = n >> 4;
    int sstride = gridDim.x * 4;
    for (int strip = blockIdx.x * 4 + wid; strip < nstrips; strip += sstride) {
        const uint4* hrow = (const uint4*)(hnbf + (size_t)(strip * 16 + c) * 64);
        f32x4 acc[4];
        #pragma unroll
        for (int no = 0; no < 4; ++no) acc[no] = (f32x4){0.f, 0.f, 0.f, 0.f};
        #pragma unroll
        for (int ko = 0; ko < 4; ++ko) {
            FragU a;
            a.u = hrow[ko * 4 + kg];
            #pragma unroll
            for (int no = 0; no < 4; ++no) {
                FragU b;
                b.u = sW[(ko * 4 + no) * 64 + lane];
                acc[no] = __builtin_amdgcn_mfma_f32_16x16x32_bf16(a.s, b.s, acc[no], 0, 0, 0);
            }
        }
        float p[4];
        #pragma unroll
        for (int r = 0; r < 4; ++r) {
            p[r] = 0.f;
            #pragma unroll
            for (int no = 0; no < 4; ++no)
                p[r] += fmaxf(acc[no][r] + b1v[no], 0.f) * w2v[no];
        }
        #pragma unroll
        for (int r = 0; r < 4; ++r) {
            p[r] += __shfl_xor(p[r], 1, 64);
            p[r] += __shfl_xor(p[r], 2, 64);
            p[r] += __shfl_xor(p[r], 4, 64);
            p[r] += __shfl_xor(p[r], 8, 64);
        }
        if (c == 0) {
            int row = strip * 16 + kg * 4;
            #pragma unroll
            for (int r = 0; r < 4; ++r) out[row + r] = p[r] + b2v;
        }
    }
}

extern "C" void kernel_launch(void* const* d_in, const int* in_sizes, int n_in,
                              void* d_out, int out_size, void* d_ws, size_t ws_size,
                              hipStream_t stream) {
    const float* x   = (const float*)d_in[0];
    const int*   ei  = (const int*)d_in[1];
    const float* Wn0 = (const float*)d_in[2];
    const float* b0  = (const float*)d_in[3];
    const float* Wr0 = (const float*)d_in[4];
    const float* g0  = (const float*)d_in[5];
    const float* be0 = (const float*)d_in[6];
    const float* Wn1 = (const float*)d_in[7];
    const float* b1  = (const float*)d_in[8];
    const float* Wr1 = (const float*)d_in[9];
    const float* g1  = (const float*)d_in[10];
    const float* be1 = (const float*)d_in[11];
    const float* Wc1 = (const float*)d_in[12];
    const float* bc1 = (const float*)d_in[13];
    const float* Wc2 = (const float*)d_in[14];
    const float* bc2 = (const float*)d_in[15];
    float* out = (float*)d_out;

    const int N = in_sizes[0] / HID;
    const int E = in_sizes[1] / 2;
    const int* srcv = ei;
    const int* tgtv = ei + E;

    size_t o = 0;
    auto carve = [&](size_t bytes) {
        void* p = (char*)d_ws + o;
        o += (bytes + 255) & ~(size_t)255;
        return p;
    };
    int* deg       = (int*)carve((size_t)N * 4);
    int* off       = (int*)carve((size_t)(N + 1) * 4);
    int* csr       = (int*)carve((size_t)E * 4);
    float* bufA    = (float*)carve((size_t)N * HID * 4);   // mean0 (bf16 alias) then h1 fp32
    float* bufB    = (float*)carve((size_t)N * HID * 4);   // h0 fp32 then mean1 (bf16 alias)
    uint32_t* fbf  = (uint32_t*)carve((size_t)N * HID * 2);  // bf16: x, h0, then h1
    uint32_t* Wp0  = (uint32_t*)carve(4096 * 16);
    uint32_t* Wp1  = (uint32_t*)carve(4096 * 16);
    uint32_t* Wcp  = (uint32_t*)carve(1024 * 16);
    int* partials  = (int*)carve(1024 * 4);
    float* stats0  = (float*)carve(256 * 4);
    float* stats1  = (float*)carve(256 * 4);
    float* params0 = (float*)carve(256 * 4);
    float* params1 = (float*)carve(256 * 4);
    (void)ws_size; (void)n_in; (void)out_size;

    uint32_t* mean0 = (uint32_t*)bufA;  // layer0 mean (bf16), dead once sage1 writes bufA
    uint32_t* mean1 = (uint32_t*)bufB;  // layer1 mean (bf16), overwrites dead h0 fp32

    hipMemsetAsync(deg, 0, (size_t)N * 4, stream);
    hipMemsetAsync(stats0, 0, 256 * 4, stream);
    hipMemsetAsync(stats1, 0, 256 * 4, stream);

    int eblocks = (E + 255) / 256;
    int nparts = (N + 1023) / 1024;
    int npb = (N + 7) / 8;  // nodes per XCD bucket

    hist_kernel<<<eblocks, 256, 0, stream>>>(tgtv, deg, E);
    partial_sum_kernel<<<nparts, 256, 0, stream>>>(deg, partials, N);
    scan_partials_kernel<<<1, 64, 0, stream>>>(partials, nparts);
    scan_final_kernel<<<nparts, 256, 0, stream>>>(deg, partials, off, N, E);
    hipMemsetAsync(deg, 0, (size_t)N * 4, stream);
    fill_kernel<<<2048, 256, 0, stream>>>(srcv, tgtv, off, deg, csr, E, npb);

    pack_w_kernel<<<16, 256, 0, stream>>>(Wn0, Wr0, Wp0);
    pack_w_kernel<<<16, 256, 0, stream>>>(Wn1, Wr1, Wp1);
    pack_wc_kernel<<<4, 256, 0, stream>>>(Wc1, Wcp);

    int aggblocks = (N * 64 + 255) / 256;
    float invn = 1.0f / (float)N;

    // layer 0
    f32_to_bf16_kernel<<<aggblocks, 256, 0, stream>>>(x, fbf, N * 64);
    aggregate_bf16_kernel<<<aggblocks, 256, 0, stream>>>(fbf, off, csr, mean0, N);
    sage_mfma_kernel<<<256, 256, 0, stream>>>(mean0, fbf, Wp0, b0, bufB, stats0, N);
    bnparam_kernel<<<1, 128, 0, stream>>>(stats0, g0, be0, params0, invn);
    norm_relu_kernel<<<aggblocks, 256, 0, stream>>>(bufB, nullptr, fbf, params0, N * 64);

    // layer 1
    aggregate_bf16_kernel<<<aggblocks, 256, 0, stream>>>(fbf, off, csr, mean1, N);
    sage_mfma_kernel<<<256, 256, 0, stream>>>(mean1, fbf, Wp1, b1, bufA, stats1, N);
    bnparam_kernel<<<1, 128, 0, stream>>>(stats1, g1, be1, params1, invn);
    norm_relu_kernel<<<aggblocks, 256, 0, stream>>>(bufA, nullptr, fbf, params1, N * 64);

    // classifier (reads bf16 h1 from fbf)
    classifier_mfma_kernel<<<256, 256, 0, stream>>>(fbf, Wcp, bc1, Wc2, bc2, out, N);
}